// Round 11
// baseline (283.917 us; speedup 1.0000x reference)
//
#include <hip/hip_runtime.h>
#include <hip/hip_bf16.h>

typedef unsigned short u16;
typedef __attribute__((ext_vector_type(4))) float floatx4;
typedef __attribute__((ext_vector_type(8))) __bf16 bf16x8;

// ---------- helpers ----------
__device__ __forceinline__ u16 f2bf(float f) {
  unsigned int x = __builtin_bit_cast(unsigned int, f);
  unsigned int r = (x + 0x7fffu + ((x >> 16) & 1u)) >> 16;
  return (u16)r;
}
__device__ __forceinline__ float bf2f(u16 u) {
  unsigned int x = ((unsigned int)u) << 16;
  return __builtin_bit_cast(float, x);
}
__device__ __forceinline__ floatx4 mfma16(bf16x8 a, bf16x8 b, floatx4 c) {
  return __builtin_amdgcn_mfma_f32_16x16x32_bf16(a, b, c, 0, 0, 0);
}
__device__ __forceinline__ void gload16(const u16* g, u16* l) {
  __builtin_amdgcn_global_load_lds(
      (const __attribute__((address_space(1))) unsigned int*)g,
      (__attribute__((address_space(3))) unsigned int*)l, 16, 0, 0);
}
#define SCHEDB() __builtin_amdgcn_sched_barrier(0)
#define SBAR() __builtin_amdgcn_s_barrier()

// ---------- sizes ----------
#define BB 2
#define SS 2048
#define DM 2048
#define HH 16
#define PCOLS 6144   // qsem 1024 | ksem 1024 | qgeo 1024 | kgeo 1024 | v 2048

// ---------- prep kernels ----------
__global__ void convert_bf16_k(const float* __restrict__ src, u16* __restrict__ dst, size_t n) {
  size_t i = ((size_t)blockIdx.x * blockDim.x + threadIdx.x) * 4;
  if (i + 3 >= n) { for (size_t j = i; j < n; ++j) dst[j] = f2bf(src[j]); return; }
  float4 v = *(const float4*)&src[i];
  ushort4 o; o.x = f2bf(v.x); o.y = f2bf(v.y); o.z = f2bf(v.z); o.w = f2bf(v.w);
  *(ushort4*)&dst[i] = o;
}

// all 6 weight transposes in one launch. dst[c][r] = bf16(src[r][c]), rows = 2048.
__global__ void transpose_all_k(const float* w0, const float* w1, const float* w2,
                                const float* w3, const float* w4, const float* w5,
                                u16* __restrict__ WcatT, u16* __restrict__ WoT) {
  __shared__ float tile[32][33];
  const int z = blockIdx.z;
  const float* src; u16* dst; int cols;
  if (z == 0)      { src = w0; dst = WcatT;                        cols = 1024; }
  else if (z == 1) { src = w1; dst = WcatT + (size_t)1024 * 2048;  cols = 1024; }
  else if (z == 2) { src = w2; dst = WcatT + (size_t)2048 * 2048;  cols = 1024; }
  else if (z == 3) { src = w3; dst = WcatT + (size_t)3072 * 2048;  cols = 1024; }
  else if (z == 4) { src = w4; dst = WcatT + (size_t)4096 * 2048;  cols = 2048; }
  else             { src = w5; dst = WoT;                          cols = 2048; }
  int c0 = blockIdx.x * 32;
  if (c0 >= cols) return;
  int r0 = blockIdx.y * 32;
  int tx = threadIdx.x, ty = threadIdx.y;
#pragma unroll
  for (int i = 0; i < 4; ++i)
    tile[ty + i * 8][tx] = src[(size_t)(r0 + ty + i * 8) * cols + c0 + tx];
  __syncthreads();
#pragma unroll
  for (int i = 0; i < 4; ++i)
    dst[(size_t)(c0 + ty + i * 8) * 2048 + r0 + tx] = f2bf(tile[tx][ty + i * 8]);
}

// V transpose: P cols [4096..6144) (bf16) -> VtG[(b*2048 + h*128+dv)][s]
__global__ void vtrans_k(const u16* __restrict__ P, u16* __restrict__ VtG) {
  __shared__ u16 t[32][33];
  int b = blockIdx.z;
  int c0 = blockIdx.x * 32;   // combined (h,dv) index
  int s0 = blockIdx.y * 32;
  int tx = threadIdx.x, ty = threadIdx.y;
#pragma unroll
  for (int i = 0; i < 4; ++i)
    t[ty + i * 8][tx] = P[((size_t)b * SS + s0 + ty + i * 8) * PCOLS + 4096 + c0 + tx];
  __syncthreads();
#pragma unroll
  for (int i = 0; i < 4; ++i)
    VtG[((size_t)b * 2048 + c0 + ty + i * 8) * SS + s0 + tx] = t[tx][ty + i * 8];
}

__global__ void rope_table_k(float* __restrict__ cosT, float* __restrict__ sinT) {
  int idx = blockIdx.x * 256 + threadIdx.x;       // 2048*32
  int s = idx >> 5, d = idx & 31;
  double inv = pow(10000.0, -(double)d / 32.0);
  double ang = (double)s * inv;
  cosT[idx] = (float)cos(ang);
  sinT[idx] = (float)sin(ang);
}

// in-place RoPE on P's qgeo (cols 2048..3071) and kgeo (cols 3072..4095)
__global__ void rope_apply_k(u16* __restrict__ P, const float* __restrict__ cosT,
                             const float* __restrict__ sinT) {
  int idx = blockIdx.x * 256 + threadIdx.x;       // rows(4096)*2*16*32
  int d = idx & 31, h = (idx >> 5) & 15, reg = (idx >> 9) & 1, row = idx >> 10;
  int s = row & (SS - 1);
  size_t base = (size_t)row * PCOLS + (reg ? 3072 : 2048) + h * 64 + d;
  float x1 = bf2f(P[base]), x2 = bf2f(P[base + 32]);
  float c = cosT[s * 32 + d], sn = sinT[s * 32 + d];
  P[base] = f2bf(x1 * c - x2 * sn);
  P[base + 32] = f2bf(x1 * sn + x2 * c);
}

// ---------- pipelined GEMM with cross-phase register prefetch ----------
// C(MxN) = A(MxK,bf16)*Bt(NxK,bf16)^T. BM=128, BN=256, BK=64, 512 thr (8 waves 2Mx4N).
// LDS TRIPLE-buffered per K-tile (buf = t%3): A 3x16KB @0, B 3x32KB @24576 u16 = 144 KB.
// Per tile: {SBAR; stage(t+2); [ph kh0: read(t,kh1)->setB; MFMA(setA)];
//            vmcnt(6); SBAR; [ph kh1: read(t+1,kh0)->setA; MFMA(setB)]}.
// Reads for the NEXT phase issue BEFORE this phase's MFMA -> LDS pipe drains the
// prefetch under the MFMA burst (compiler emits precise per-register lgkmcnt).
// Hazards: stage(t+2) targets buf (t+2)%3, never the buf read this tile; reads of a
// buf complete before their consuming MFMA issue, which precedes each wave's next
// SBAR arrival -> entry-SBAR protects overwrite. vmcnt(6)+SBAR makes S(t+1)
// collectively visible before R(t+1,kh0). Never vmcnt(0) mid-loop.
template <bool OUTF32>
__global__ __launch_bounds__(512, 1)
void gemm3p_k(const u16* __restrict__ A, const u16* __restrict__ Bt,
              void* __restrict__ Cout, int M, int N, int K) {
  __shared__ alignas(16) u16 lds[73728];   // 144 KiB
  const int tid = threadIdx.x;
  const int wid = tid >> 6, lane = tid & 63;
  const int lr = lane & 15, lg = lane >> 4;
  const int wr = wid >> 2, wc = wid & 3;
  const int m0 = blockIdx.y * 128, n0 = blockIdx.x * 256;
  const int NT = K >> 6;

  // read-side: row*32 + swizzled granule ((row>>1)&3 == (lr>>1)&3 for 16-aligned rows)
  const int aoff = lr * 32 + ((lg ^ ((lr >> 1) & 3)) * 8);

  // staging: thread -> row tid>>2 (0..127), dest granule tid&3,
  // source granule (tid&3)^((tid>>3)&3) (inverse swizzle)
  const int srow = tid >> 2;
  const int sgl = (((tid & 3) ^ ((tid >> 3) & 3)) * 8);
  const u16* Asrc = A + (size_t)(m0 + srow) * K + sgl;
  const u16* Bsrc = Bt + (size_t)(n0 + srow) * K + sgl;

  floatx4 acc[4][4];
#pragma unroll
  for (int m = 0; m < 4; ++m)
#pragma unroll
    for (int n = 0; n < 4; ++n) acc[m][n] = (floatx4){0.f, 0.f, 0.f, 0.f};

  // stage full tile t: A 128x64 (2 gloads) + B 256x64 (4 gloads) into buf t%3
  auto stage_tile = [&](int t) {
    if (t >= NT) return;
    const int b = t % 3;
    u16* Ad = lds + b * 8192;             // [kh][128][32]
    u16* Bd = lds + 24576 + b * 16384;    // [kh][256][32]
#pragma unroll
    for (int kh = 0; kh < 2; ++kh) {
      gload16(Asrc + t * 64 + kh * 32, Ad + kh * 4096 + wid * 512);
      const u16* sb = Bsrc + t * 64 + kh * 32;
      gload16(sb, Bd + kh * 8192 + wid * 512);
      gload16(sb + (size_t)128 * K, Bd + kh * 8192 + 4096 + wid * 512);
    }
  };

  bf16x8 afA[4], bvA[4], afB[4], bvB[4];

  auto rdA = [&](bf16x8* af, int t, int kh) {
    const u16* Ab = lds + (t % 3) * 8192 + kh * 4096;
#pragma unroll
    for (int m = 0; m < 4; ++m)
      af[m] = *(const bf16x8*)&Ab[(wr * 64 + m * 16) * 32 + aoff];
  };
  auto rdB = [&](bf16x8* bv, int t, int kh) {
    const u16* Bb = lds + 24576 + (t % 3) * 16384 + kh * 8192;
#pragma unroll
    for (int n = 0; n < 4; ++n)
      bv[n] = *(const bf16x8*)&Bb[(wc * 64 + n * 16) * 32 + aoff];
  };

  // prologue: tiles 0,1 staged; wait own S(0) loads; barrier; preload (0,kh0)
  stage_tile(0);
  stage_tile(1);
  asm volatile("s_waitcnt vmcnt(6)" ::: "memory");
  SCHEDB(); SBAR(); SCHEDB();
  rdA(afA, 0, 0); rdB(bvA, 0, 0);

#pragma unroll 1
  for (int t = 0; t < NT; ++t) {
    SCHEDB(); SBAR(); SCHEDB();          // entry barrier (protects stage overwrite)
    stage_tile(t + 2);
    SCHEDB();
    // phase kh0: prefetch (t,kh1) into set B; compute set A
    rdA(afB, t, 1); rdB(bvB, t, 1);
    SCHEDB();
    __builtin_amdgcn_s_setprio(1);
#pragma unroll
    for (int m = 0; m < 4; ++m)
#pragma unroll
      for (int n = 0; n < 4; ++n)
        acc[m][n] = mfma16(afA[m], bvA[n], acc[m][n]);
    __builtin_amdgcn_s_setprio(0);
    SCHEDB();
    if (t + 2 < NT) asm volatile("s_waitcnt vmcnt(6)" ::: "memory");
    else            asm volatile("s_waitcnt vmcnt(0)" ::: "memory");
    SCHEDB(); SBAR(); SCHEDB();          // mid barrier: S(t+1) collectively visible
    // phase kh1: prefetch (t+1,kh0) into set A; compute set B
    if (t + 1 < NT) { rdA(afA, t + 1, 0); rdB(bvA, t + 1, 0); }
    SCHEDB();
    __builtin_amdgcn_s_setprio(1);
#pragma unroll
    for (int m = 0; m < 4; ++m)
#pragma unroll
      for (int n = 0; n < 4; ++n)
        acc[m][n] = mfma16(afB[m], bvB[n], acc[m][n]);
    __builtin_amdgcn_s_setprio(0);
  }

  // epilogue
#pragma unroll
  for (int m = 0; m < 4; ++m) {
    int row0 = m0 + wr * 64 + m * 16 + lg * 4;
#pragma unroll
    for (int n = 0; n < 4; ++n) {
      int col = n0 + wc * 64 + n * 16 + lr;
#pragma unroll
      for (int r = 0; r < 4; ++r) {
        size_t off = (size_t)(row0 + r) * N + col;
        if (OUTF32) ((float*)Cout)[off] = acc[m][n][r];
        else        ((u16*)Cout)[off] = f2bf(acc[m][n][r]);
      }
    }
  }
}

// ---------- flash attention: swapped QK^T, LDS K/V double-buffer, counted vmcnt ----------
__device__ __forceinline__ bf16x8 load_scaled(const u16* p, float s) {
  uint4 raw = *(const uint4*)p;
  const u16* ru = (const u16*)&raw;
  bf16x8 out;
#pragma unroll
  for (int j = 0; j < 8; ++j) out[j] = (__bf16)(bf2f(ru[j]) * s);
  return out;
}

__global__ __launch_bounds__(256, 2)
void attn_k(const u16* __restrict__ P, const u16* __restrict__ VtG,
            const float* __restrict__ gate, u16* __restrict__ AttO) {
  // grid: x = 256 (pair 0..15 x 16 heads), y = B. Block does q-tiles pairi and 31-pairi:
  // (pairi+1) + (32-pairi) = 33 kv-iterations per block — perfect balance.
  const int pairi = blockIdx.x >> 4;
  const int h = blockIdx.x & 15;
  const int b = blockIdx.y;
  const int tid = threadIdx.x, wid = tid >> 6, lane = tid & 63;
  const int lr = lane & 15, lg = lane >> 4;
  const size_t rowb = (size_t)b * SS;

  const float g = 1.f / (1.f + __expf(-gate[h]));
  const float ssc = g * 0.125f;          // g / sqrt(DS)
  const float gsc = (1.f - g) * 0.125f;  // (1-g) / sqrt(DG)

  // double-buffered tiles, [rows][64] linear, granule-swizzled: byte ^= (row&7)<<4
  __shared__ alignas(16) u16 Ks[2][64 * 64];
  __shared__ alignas(16) u16 Kg[2][64 * 64];
  __shared__ alignas(16) u16 Vt[2][128 * 64];
  __shared__ alignas(16) u16 Pw[4][16 * 64];
  // 72 KB -> 2 blocks/CU

  const int strow = tid >> 3;                 // 0..31
  const int stg = ((tid & 7) ^ (strow & 7)) * 8;
  const int swz = lr & 7;                     // read-side swizzle (row&7 == lr&7)

  // stage K_sem/K_geo/V tile: 8 gload_lds per thread (K 4, V 4)
  auto stageKV = [&](int kv0, int buf) {
    const u16* ks = P + (rowb + kv0 + strow) * PCOLS + 1024 + h * 64 + stg;
    const u16* gs = P + (rowb + kv0 + strow) * PCOLS + 3072 + h * 64 + stg;
    gload16(ks, &Ks[buf][wid * 512]);
    gload16(gs, &Kg[buf][wid * 512]);
    gload16(ks + (size_t)32 * PCOLS, &Ks[buf][2048 + wid * 512]);
    gload16(gs + (size_t)32 * PCOLS, &Kg[buf][2048 + wid * 512]);
    const u16* vs = VtG + ((size_t)b * 2048 + h * 128 + strow) * SS + kv0 + stg;
#pragma unroll
    for (int c = 0; c < 4; ++c)
      gload16(vs + (size_t)(c * 32) * SS, &Vt[buf][c * 2048 + wid * 512]);
  };

  for (int half = 0; half < 2; ++half) {
    const int qb = half ? (31 - pairi) : pairi;
    const int q0 = qb * 64;

    // Q fragments (B-operand: lane holds Q[q = q0+wid*16+lr][k = kk*32+lg*8..+7])
    const u16* qbase = P + (rowb + q0 + wid * 16 + lr) * PCOLS + h * 64;
    bf16x8 qs[2], qg[2];
#pragma unroll
    for (int kk = 0; kk < 2; ++kk) {
      qs[kk] = load_scaled(qbase + kk * 32 + lg * 8, ssc);
      qg[kk] = load_scaled(qbase + 2048 + kk * 32 + lg * 8, gsc);
    }

    float m_r = -1e30f, l_r = 0.f;
    floatx4 o[8];
#pragma unroll
    for (int n = 0; n < 8; ++n) o[n] = (floatx4){0.f, 0.f, 0.f, 0.f};

    const int nkv = q0 + 64;

    // prologue: tile 0 staged and drained (once per half)
    stageKV(0, 0);
    asm volatile("s_waitcnt vmcnt(0)" ::: "memory");
    SCHEDB(); SBAR(); SCHEDB();

    for (int kv0 = 0; kv0 < nkv; kv0 += 64) {
      const int cur = (kv0 >> 6) & 1;
      const bool more = (kv0 + 64 < nkv);

      // stage next tile into other buffer (its last reads ended before the
      // previous iteration's terminal barrier); counted wait for current tile
      if (more) stageKV(kv0 + 64, cur ^ 1);
      SCHEDB();
      if (more) asm volatile("s_waitcnt vmcnt(8)" ::: "memory");
      else      asm volatile("s_waitcnt vmcnt(0)" ::: "memory");
      SCHEDB(); SBAR(); SCHEDB();

      // swapped QK^T: lane holds score(q=q0+wid*16+lr, k=kv0+s*16+lg*4+r)
      floatx4 sc[4];
#pragma unroll
      for (int s = 0; s < 4; ++s) sc[s] = (floatx4){0.f, 0.f, 0.f, 0.f};
#pragma unroll
      for (int kk = 0; kk < 2; ++kk) {
#pragma unroll
        for (int s = 0; s < 4; ++s) {
          bf16x8 kf = *(const bf16x8*)&Ks[cur][(s * 16 + lr) * 64 + ((kk * 4 + lg) ^ swz) * 8];
          bf16x8 gf = *(const bf16x8*)&Kg[cur][(s * 16 + lr) * 64 + ((kk * 4 + lg) ^ swz) * 8];
          sc[s] = mfma16(kf, qs[kk], sc[s]);
          sc[s] = mfma16(gf, qg[kk], sc[s]);
        }
      }

      // per-lane softmax over this lane's 16 values (its q-row = lr)
      const int qrow = q0 + wid * 16 + lr;
      const bool needmask = (kv0 + 63 > q0 + wid * 16);
      float vv[4][4];
      float vmax = -1e30f;
#pragma unroll
      for (int s = 0; s < 4; ++s)
#pragma unroll
        for (int r = 0; r < 4; ++r) {
          float val = sc[s][r];
          if (needmask) val = (kv0 + s * 16 + lg * 4 + r <= qrow) ? val : -1e30f;
          vv[s][r] = val;
          vmax = fmaxf(vmax, val);
        }
      vmax = fmaxf(vmax, __shfl_xor(vmax, 16));
      vmax = fmaxf(vmax, __shfl_xor(vmax, 32));
      float mnew = fmaxf(m_r, vmax);
      float corr = __expf(m_r - mnew);
      float psum = 0.f;
#pragma unroll
      for (int s = 0; s < 4; ++s)
#pragma unroll
        for (int r = 0; r < 4; ++r) {
          vv[s][r] = __expf(vv[s][r] - mnew);
          psum += vv[s][r];
        }
      psum += __shfl_xor(psum, 16);
      psum += __shfl_xor(psum, 32);
      l_r = l_r * corr + psum;
      m_r = mnew;

      // pack P to bf16 pairs, write swizzled: value k=s*16+lg*4+2t(,+1) at row lr
#pragma unroll
      for (int s = 0; s < 4; ++s)
#pragma unroll
        for (int t = 0; t < 2; ++t) {
          unsigned int w;
          asm("v_cvt_pk_bf16_f32 %0, %1, %2" : "=v"(w) : "v"(vv[s][2 * t]), "v"(vv[s][2 * t + 1]));
          int u16off = lr * 64 + ((s * 2 + (lg >> 1)) ^ swz) * 8 + (lg & 1) * 4 + t * 2;
          *(unsigned int*)&Pw[wid][u16off] = w;
        }

      // redistribute corr to o-rows (o[n][r] is q-row lg*4+r)
      float crr[4];
#pragma unroll
      for (int r = 0; r < 4; ++r) crr[r] = __shfl(corr, lg * 4 + r);
#pragma unroll
      for (int n = 0; n < 8; ++n)
#pragma unroll
        for (int r = 0; r < 4; ++r) o[n][r] *= crr[r];

      asm volatile("s_waitcnt lgkmcnt(0)" ::: "memory");
      SCHEDB();
      // PV: A = P[q=lr][k-chunk], B = Vt[dv=n*16+lr][k-chunk]
      bf16x8 pa0 = *(const bf16x8*)&Pw[wid][lr * 64 + (lg ^ swz) * 8];
      bf16x8 pa1 = *(const bf16x8*)&Pw[wid][lr * 64 + ((4 + lg) ^ swz) * 8];
#pragma unroll
      for (int n = 0; n < 8; ++n) {
        bf16x8 vb0 = *(const bf16x8*)&Vt[cur][(n * 16 + lr) * 64 + (lg ^ swz) * 8];
        bf16x8 vb1 = *(const bf16x8*)&Vt[cur][(n * 16 + lr) * 64 + ((4 + lg) ^ swz) * 8];
        o[n] = mfma16(pa0, vb0, o[n]);
        o[n] = mfma16(pa1, vb1, o[n]);
      }
      SCHEDB(); SBAR(); SCHEDB();   // terminal barrier: protects buf cur^1 overwrite
    }

    float linv = 1.f / l_r;
    float lnv[4];
#pragma unroll
    for (int r = 0; r < 4; ++r) lnv[r] = __shfl(linv, lg * 4 + r);
#pragma unroll
    for (int n = 0; n < 8; ++n)
#pragma unroll
      for (int r = 0; r < 4; ++r) {
        float val = o[n][r] * lnv[r];
        AttO[(rowb + q0 + wid * 16 + lg * 4 + r) * (size_t)(HH * 128) + h * 128 + n * 16 + lr] =
            f2bf(val);
      }
  }
}

// ---------- launch ----------
extern "C" void kernel_launch(void* const* d_in, const int* in_sizes, int n_in,
                              void* d_out, int out_size, void* d_ws, size_t ws_size,
                              hipStream_t stream) {
  const float* x       = (const float*)d_in[0];
  const float* wq_sem  = (const float*)d_in[1];
  const float* wk_sem  = (const float*)d_in[2];
  const float* wq_geo  = (const float*)d_in[3];
  const float* wk_geo  = (const float*)d_in[4];
  const float* wv      = (const float*)d_in[5];
  const float* wo      = (const float*)d_in[6];
  const float* gate    = (const float*)d_in[7];

  char* ws = (char*)d_ws;
  u16* Xbf   = (u16*)(ws);
  u16* WcatT = (u16*)(ws + 16777216);
  u16* WoT   = (u16*)(ws + 16777216 + 25165824);
  u16* P     = (u16*)(ws + 16777216 + 25165824 + 8388608);
  float* cosT = (float*)(ws + 16777216 + 25165824 + 8388608 + 50331648);
  float* sinT = cosT + 2048 * 32;
  u16* AttO = Xbf;    // Xbf dead after projection GEMM
  u16* VtG  = WcatT;  // WcatT dead after projection GEMM

  dim3 tb(32, 8);
  convert_bf16_k<<<8192, 256, 0, stream>>>(x, Xbf, (size_t)4096 * 2048);
  transpose_all_k<<<dim3(64, 64, 6), tb, 0, stream>>>(wq_sem, wk_sem, wq_geo, wk_geo,
                                                      wv, wo, WcatT, WoT);
  rope_table_k<<<256, 256, 0, stream>>>(cosT, sinT);

  // proj: 24x32 = 768 blocks = 3 balanced rounds
  gemm3p_k<false><<<dim3(24, 32), 512, 0, stream>>>(Xbf, WcatT, P, 4096, 6144, 2048);
  rope_apply_k<<<16384, 256, 0, stream>>>(P, cosT, sinT);
  vtrans_k<<<dim3(64, 64, 2), tb, 0, stream>>>(P, VtG);
  attn_k<<<dim3(256, 2), 256, 0, stream>>>(P, VtG, gate, AttO);
  // wo: 8x32 = 256 blocks = 1 balanced round
  gemm3p_k<true><<<dim3(8, 32), 512, 0, stream>>>(AttO, WoT, d_out, 4096, 2048, 2048);
}

// Round 12
// 262.486 us; speedup vs baseline: 1.0816x; 1.0816x over previous
//
#include <hip/hip_runtime.h>
#include <hip/hip_bf16.h>

typedef unsigned short u16;
typedef __attribute__((ext_vector_type(4))) float floatx4;
typedef __attribute__((ext_vector_type(8))) __bf16 bf16x8;

// ---------- helpers ----------
__device__ __forceinline__ u16 f2bf(float f) {
  unsigned int x = __builtin_bit_cast(unsigned int, f);
  unsigned int r = (x + 0x7fffu + ((x >> 16) & 1u)) >> 16;
  return (u16)r;
}
__device__ __forceinline__ float bf2f(u16 u) {
  unsigned int x = ((unsigned int)u) << 16;
  return __builtin_bit_cast(float, x);
}
__device__ __forceinline__ floatx4 mfma16(bf16x8 a, bf16x8 b, floatx4 c) {
  return __builtin_amdgcn_mfma_f32_16x16x32_bf16(a, b, c, 0, 0, 0);
}
__device__ __forceinline__ void gload16(const u16* g, u16* l) {
  __builtin_amdgcn_global_load_lds(
      (const __attribute__((address_space(1))) unsigned int*)g,
      (__attribute__((address_space(3))) unsigned int*)l, 16, 0, 0);
}
#define SCHEDB() __builtin_amdgcn_sched_barrier(0)
#define SBAR() __builtin_amdgcn_s_barrier()

// ---------- sizes ----------
#define BB 2
#define SS 2048
#define DM 2048
#define HH 16
#define PCOLS 6144   // qsem 1024 | ksem 1024 | qgeo 1024 | kgeo 1024 | v 2048

// ---------- prep kernels ----------
__global__ void convert_bf16_k(const float* __restrict__ src, u16* __restrict__ dst, size_t n) {
  size_t i = ((size_t)blockIdx.x * blockDim.x + threadIdx.x) * 4;
  if (i + 3 >= n) { for (size_t j = i; j < n; ++j) dst[j] = f2bf(src[j]); return; }
  float4 v = *(const float4*)&src[i];
  ushort4 o; o.x = f2bf(v.x); o.y = f2bf(v.y); o.z = f2bf(v.z); o.w = f2bf(v.w);
  *(ushort4*)&dst[i] = o;
}

// all 6 weight transposes in one launch. dst[c][r] = bf16(src[r][c]), rows = 2048.
__global__ void transpose_all_k(const float* w0, const float* w1, const float* w2,
                                const float* w3, const float* w4, const float* w5,
                                u16* __restrict__ WcatT, u16* __restrict__ WoT) {
  __shared__ float tile[32][33];
  const int z = blockIdx.z;
  const float* src; u16* dst; int cols;
  if (z == 0)      { src = w0; dst = WcatT;                        cols = 1024; }
  else if (z == 1) { src = w1; dst = WcatT + (size_t)1024 * 2048;  cols = 1024; }
  else if (z == 2) { src = w2; dst = WcatT + (size_t)2048 * 2048;  cols = 1024; }
  else if (z == 3) { src = w3; dst = WcatT + (size_t)3072 * 2048;  cols = 1024; }
  else if (z == 4) { src = w4; dst = WcatT + (size_t)4096 * 2048;  cols = 2048; }
  else             { src = w5; dst = WoT;                          cols = 2048; }
  int c0 = blockIdx.x * 32;
  if (c0 >= cols) return;
  int r0 = blockIdx.y * 32;
  int tx = threadIdx.x, ty = threadIdx.y;
#pragma unroll
  for (int i = 0; i < 4; ++i)
    tile[ty + i * 8][tx] = src[(size_t)(r0 + ty + i * 8) * cols + c0 + tx];
  __syncthreads();
#pragma unroll
  for (int i = 0; i < 4; ++i)
    dst[(size_t)(c0 + ty + i * 8) * 2048 + r0 + tx] = f2bf(tile[tx][ty + i * 8]);
}

// V transpose: P cols [4096..6144) (bf16) -> VtG[(b*2048 + h*128+dv)][s]
__global__ void vtrans_k(const u16* __restrict__ P, u16* __restrict__ VtG) {
  __shared__ u16 t[32][33];
  int b = blockIdx.z;
  int c0 = blockIdx.x * 32;   // combined (h,dv) index
  int s0 = blockIdx.y * 32;
  int tx = threadIdx.x, ty = threadIdx.y;
#pragma unroll
  for (int i = 0; i < 4; ++i)
    t[ty + i * 8][tx] = P[((size_t)b * SS + s0 + ty + i * 8) * PCOLS + 4096 + c0 + tx];
  __syncthreads();
#pragma unroll
  for (int i = 0; i < 4; ++i)
    VtG[((size_t)b * 2048 + c0 + ty + i * 8) * SS + s0 + tx] = t[tx][ty + i * 8];
}

__global__ void rope_table_k(float* __restrict__ cosT, float* __restrict__ sinT) {
  int idx = blockIdx.x * 256 + threadIdx.x;       // 2048*32
  int s = idx >> 5, d = idx & 31;
  double inv = pow(10000.0, -(double)d / 32.0);
  double ang = (double)s * inv;
  cosT[idx] = (float)cos(ang);
  sinT[idx] = (float)sin(ang);
}

// in-place RoPE on P's qgeo (cols 2048..3071) and kgeo (cols 3072..4095)
__global__ void rope_apply_k(u16* __restrict__ P, const float* __restrict__ cosT,
                             const float* __restrict__ sinT) {
  int idx = blockIdx.x * 256 + threadIdx.x;       // rows(4096)*2*16*32
  int d = idx & 31, h = (idx >> 5) & 15, reg = (idx >> 9) & 1, row = idx >> 10;
  int s = row & (SS - 1);
  size_t base = (size_t)row * PCOLS + (reg ? 3072 : 2048) + h * 64 + d;
  float x1 = bf2f(P[base]), x2 = bf2f(P[base + 32]);
  float c = cosT[s * 32 + d], sn = sinT[s * 32 + d];
  P[base] = f2bf(x1 * c - x2 * sn);
  P[base + 32] = f2bf(x1 * sn + x2 * c);
}

// ---------- 8-phase GEMM, 4 waves, big per-wave tile (round-5 best: 116 µs proj) ----------
template <int NFB, bool OUTF32>
__global__ __launch_bounds__(256, 1)
void gemm4_k(const u16* __restrict__ A, const u16* __restrict__ Bt,
             void* __restrict__ Cout, int M, int N, int K) {
  constexpr int BH = NFB / 2;              // bfv frags per phase
  __shared__ alignas(16) u16 lds[16384 + NFB * 8192];
  const int tid = threadIdx.x;
  const int wid = tid >> 6, lane = tid & 63;
  const int lr = lane & 15, lg = lane >> 4;
  const int m0 = blockIdx.y * 128, n0 = blockIdx.x * (NFB * 64);
  const int NT = K >> 6;                   // K-tiles of 64
  const int NSLAB = NT * 4;

  const int aoff = lr * 32 + ((lg ^ ((lr >> 1) & 3)) * 8);

  const int srow = wid * 16 + (lane >> 2);
  const int sgl = (((lane & 3) ^ ((lane >> 3) & 3)) * 8);
  const u16* Asrc = A + (size_t)(m0 + srow) * K + sgl;
  const u16* Bsrc = Bt + (size_t)(n0 + srow) * K + sgl;

  floatx4 acc[8][NFB];
#pragma unroll
  for (int m = 0; m < 8; ++m)
#pragma unroll
    for (int n = 0; n < NFB; ++n) acc[m][n] = (floatx4){0.f, 0.f, 0.f, 0.f};

  auto stgA = [&](int tile, int kh) {
    u16* d = lds + ((tile & 1) * 2 + kh) * 4096 + wid * 512;
    const u16* s = Asrc + tile * 64 + kh * 32;
#pragma unroll
    for (int c = 0; c < 2; ++c) gload16(s + (size_t)(c * 64) * K, d + c * 2048);
  };
  auto stgB = [&](int tile, int kh) {
    u16* d = lds + 16384 + ((tile & 1) * 2 + kh) * (NFB * 2048) + wid * 512;
    const u16* s = Bsrc + tile * 64 + kh * 32;
#pragma unroll
    for (int c = 0; c < NFB; ++c) gload16(s + (size_t)(c * 64) * K, d + c * 2048);
  };
  auto stage_slab = [&](int s) {
    if (s >= NSLAB) return;
    int tile = s >> 2, kind = s & 3;
    if (kind == 0) stgA(tile, 0);
    else if (kind == 1) stgB(tile, 0);
    else if (kind == 2) stgA(tile, 1);
    else stgB(tile, 1);
  };

  for (int s = 0; s < 7; ++s) stage_slab(s);
  if constexpr (NFB == 6) asm volatile("s_waitcnt vmcnt(10)" ::: "memory");
  else                    asm volatile("s_waitcnt vmcnt(8)" ::: "memory");
  SCHEDB(); SBAR(); SCHEDB();

  bf16x8 af[8], bfv[BH];

#pragma unroll 1
  for (int it = 0; it < (NT >> 1); ++it) {
    const int t = it * 2;
    const int sb = t * 4 + 6;
    const bool more = (t + 2 < NT);

#define PH(BUF, KK, NH, SL, DOVM)                                               \
    {                                                                           \
      const u16* Ab = lds + ((BUF) * 2 + (KK)) * 4096;                          \
      const u16* Bb = lds + 16384 + ((BUF) * 2 + (KK)) * (NFB * 2048);          \
      if ((NH) == 0) {                                                          \
        _Pragma("unroll") for (int m = 0; m < 8; ++m)                           \
          af[m] = *(const bf16x8*)&Ab[(m * 16) * 32 + aoff];                    \
      }                                                                         \
      _Pragma("unroll") for (int j = 0; j < BH; ++j)                            \
        bfv[j] = *(const bf16x8*)&Bb[(wid * NFB * 16 + ((NH) * BH + j) * 16) * 32 + aoff]; \
      stage_slab(sb + (SL));                                                    \
      SCHEDB(); SBAR(); SCHEDB();                                               \
      __builtin_amdgcn_s_setprio(1);                                            \
      _Pragma("unroll") for (int m = 0; m < 8; ++m)                             \
        _Pragma("unroll") for (int j = 0; j < BH; ++j)                          \
          acc[m][(NH) * BH + j] = mfma16(af[m], bfv[j], acc[m][(NH) * BH + j]); \
      __builtin_amdgcn_s_setprio(0);                                            \
      if (DOVM) {                                                               \
        if (more) {                                                             \
          if constexpr (NFB == 6) asm volatile("s_waitcnt vmcnt(10)" ::: "memory"); \
          else                    asm volatile("s_waitcnt vmcnt(8)" ::: "memory");  \
        } else {                                                                \
          asm volatile("s_waitcnt vmcnt(0)" ::: "memory");                      \
        }                                                                       \
      }                                                                         \
      SCHEDB(); SBAR(); SCHEDB();                                               \
    }

    PH(0, 0, 0, 1, 0)
    PH(0, 0, 1, 2, 0)
    PH(0, 1, 0, 3, 0)
    PH(0, 1, 1, 4, 1)
    PH(1, 0, 0, 5, 0)
    PH(1, 0, 1, 6, 0)
    PH(1, 1, 0, 7, 0)
    PH(1, 1, 1, 8, 1)
#undef PH
  }

  // epilogue
#pragma unroll
  for (int m = 0; m < 8; ++m) {
    int row0 = m0 + m * 16 + lg * 4;
#pragma unroll
    for (int n = 0; n < NFB; ++n) {
      int col = n0 + wid * NFB * 16 + n * 16 + lr;
#pragma unroll
      for (int r = 0; r < 4; ++r) {
        size_t off = (size_t)(row0 + r) * N + col;
        if (OUTF32) ((float*)Cout)[off] = acc[m][n][r];
        else        ((u16*)Cout)[off] = f2bf(acc[m][n][r]);
      }
    }
  }
}

// ---------- flash attention: swapped QK^T, per-lane softmax, pair-balanced, defer-max ----------
__device__ __forceinline__ bf16x8 load_scaled(const u16* p, float s) {
  uint4 raw = *(const uint4*)p;
  const u16* ru = (const u16*)&raw;
  bf16x8 out;
#pragma unroll
  for (int j = 0; j < 8; ++j) out[j] = (__bf16)(bf2f(ru[j]) * s);
  return out;
}

__global__ __launch_bounds__(256, 3)
void attn_k(const u16* __restrict__ P, const u16* __restrict__ VtG,
            const float* __restrict__ gate, u16* __restrict__ AttO) {
  // grid: x = 256 (pair 0..15 x 16 heads), y = B. Block does q-tiles pairi and 31-pairi
  // (64 rows each): (pairi+1) + (32-pairi) = 33 kv-iterations per block — perfect balance.
  const int pairi = blockIdx.x >> 4;
  const int h = blockIdx.x & 15;
  const int b = blockIdx.y;
  const int tid = threadIdx.x, wid = tid >> 6, lane = tid & 63;
  const int lr = lane & 15, lg = lane >> 4;
  const size_t rowb = (size_t)b * SS;

  const float g = 1.f / (1.f + __expf(-gate[h]));
  const float ssc = g * 0.125f;          // g / sqrt(DS)
  const float gsc = (1.f - g) * 0.125f;  // (1-g) / sqrt(DG)

  // all tiles [rows][64] linear, granule-swizzled: byte ^= (row&7)<<4
  __shared__ alignas(16) u16 Ks[64 * 64];
  __shared__ alignas(16) u16 Kg[64 * 64];
  __shared__ alignas(16) u16 Vt[128 * 64];
  __shared__ alignas(16) u16 Pw[4][16 * 64];

  const int strow = tid >> 3;                 // 0..31
  const int stg = ((tid & 7) ^ (strow & 7)) * 8;
  const int swz = lr & 7;                     // read-side swizzle (row&7 == lr&7)

  for (int half = 0; half < 2; ++half) {
    const int qb = half ? (31 - pairi) : pairi;
    const int q0 = qb * 64;

    // Q fragments (B-operand: lane holds Q[q = q0+wid*16+lr][k = kk*32+lg*8..+7])
    const u16* qbase = P + (rowb + q0 + wid * 16 + lr) * PCOLS + h * 64;
    bf16x8 qs[2], qg[2];
#pragma unroll
    for (int kk = 0; kk < 2; ++kk) {
      qs[kk] = load_scaled(qbase + kk * 32 + lg * 8, ssc);
      qg[kk] = load_scaled(qbase + 2048 + kk * 32 + lg * 8, gsc);
    }

    float m_r = -1e30f, l_r = 0.f;
    floatx4 o[8];
#pragma unroll
    for (int n = 0; n < 8; ++n) o[n] = (floatx4){0.f, 0.f, 0.f, 0.f};

    const int nkv = q0 + 64;
    for (int kv0 = 0; kv0 < nkv; kv0 += 64) {
      __syncthreads();
      {  // stage K_sem/K_geo rows 0..63 via global_load_lds (linear dest, pre-swizzled src)
        const u16* ks = P + (rowb + kv0 + strow) * PCOLS + 1024 + h * 64 + stg;
        const u16* gs = P + (rowb + kv0 + strow) * PCOLS + 3072 + h * 64 + stg;
        gload16(ks, Ks + wid * 512);
        gload16(gs, Kg + wid * 512);
        gload16(ks + (size_t)32 * PCOLS, Ks + 2048 + wid * 512);
        gload16(gs + (size_t)32 * PCOLS, Kg + 2048 + wid * 512);
      }
      {  // stage V^T rows (dv) 0..127
        const u16* vs = VtG + ((size_t)b * 2048 + h * 128 + strow) * SS + kv0 + stg;
#pragma unroll
        for (int c = 0; c < 4; ++c)
          gload16(vs + (size_t)(c * 32) * SS, Vt + c * 2048 + wid * 512);
      }
      __syncthreads();   // compiler drains vmcnt before barrier

      // swapped QK^T: lane holds score(q=q0+wid*16+lr, k=kv0+s*16+lg*4+r)
      floatx4 sc[4];
#pragma unroll
      for (int s = 0; s < 4; ++s) sc[s] = (floatx4){0.f, 0.f, 0.f, 0.f};
#pragma unroll
      for (int kk = 0; kk < 2; ++kk) {
#pragma unroll
        for (int s = 0; s < 4; ++s) {
          bf16x8 kf = *(const bf16x8*)&Ks[(s * 16 + lr) * 64 + ((kk * 4 + lg) ^ swz) * 8];
          bf16x8 gf = *(const bf16x8*)&Kg[(s * 16 + lr) * 64 + ((kk * 4 + lg) ^ swz) * 8];
          sc[s] = mfma16(kf, qs[kk], sc[s]);
          sc[s] = mfma16(gf, qg[kk], sc[s]);
        }
      }

      // per-lane softmax over this lane's 16 values (its q-row = lr)
      const int qrow = q0 + wid * 16 + lr;
      const bool needmask = (kv0 + 63 > q0 + wid * 16);
      float vv[4][4];
      float vmax = -1e30f;
#pragma unroll
      for (int s = 0; s < 4; ++s)
#pragma unroll
        for (int r = 0; r < 4; ++r) {
          float val = sc[s][r];
          if (needmask) val = (kv0 + s * 16 + lg * 4 + r <= qrow) ? val : -1e30f;
          vv[s][r] = val;
          vmax = fmaxf(vmax, val);
        }
      vmax = fmaxf(vmax, __shfl_xor(vmax, 16));
      vmax = fmaxf(vmax, __shfl_xor(vmax, 32));

      // T13 defer-max: if row max grew by <= 8 for ALL rows of this wave, keep m_r
      // (P bounded by e^8 — same relative bf16 precision) and skip the O-rescale.
      const bool defer = __all(vmax - m_r <= 8.0f);
      const float mnew = defer ? m_r : fmaxf(m_r, vmax);
      float psum = 0.f;
#pragma unroll
      for (int s = 0; s < 4; ++s)
#pragma unroll
        for (int r = 0; r < 4; ++r) {
          vv[s][r] = __expf(vv[s][r] - mnew);
          psum += vv[s][r];
        }
      psum += __shfl_xor(psum, 16);
      psum += __shfl_xor(psum, 32);

      // pack P to bf16 pairs, write swizzled: value k=s*16+lg*4+2t(,+1) at row lr
#pragma unroll
      for (int s = 0; s < 4; ++s)
#pragma unroll
        for (int t = 0; t < 2; ++t) {
          unsigned int w;
          asm("v_cvt_pk_bf16_f32 %0, %1, %2" : "=v"(w) : "v"(vv[s][2 * t]), "v"(vv[s][2 * t + 1]));
          int u16off = lr * 64 + ((s * 2 + (lg >> 1)) ^ swz) * 8 + (lg & 1) * 4 + t * 2;
          *(unsigned int*)&Pw[wid][u16off] = w;
        }

      // rescale (skipped when deferred) — VALU here overlaps the Pw ds_write latency
      if (!defer) {
        float corr = __expf(m_r - mnew);
        l_r *= corr;
        m_r = mnew;
        float crr[4];
#pragma unroll
        for (int r = 0; r < 4; ++r) crr[r] = __shfl(corr, lg * 4 + r);
#pragma unroll
        for (int n = 0; n < 8; ++n)
#pragma unroll
          for (int r = 0; r < 4; ++r) o[n][r] *= crr[r];
      }
      l_r += psum;

      asm volatile("s_waitcnt lgkmcnt(0)" ::: "memory");
      SCHEDB();
      // PV: A = P[q=lr][k-chunk], B = Vt[dv=n*16+lr][k-chunk]
      bf16x8 pa0 = *(const bf16x8*)&Pw[wid][lr * 64 + (lg ^ swz) * 8];
      bf16x8 pa1 = *(const bf16x8*)&Pw[wid][lr * 64 + ((4 + lg) ^ swz) * 8];
#pragma unroll
      for (int n = 0; n < 8; ++n) {
        bf16x8 vb0 = *(const bf16x8*)&Vt[(n * 16 + lr) * 64 + (lg ^ swz) * 8];
        bf16x8 vb1 = *(const bf16x8*)&Vt[(n * 16 + lr) * 64 + ((4 + lg) ^ swz) * 8];
        o[n] = mfma16(pa0, vb0, o[n]);
        o[n] = mfma16(pa1, vb1, o[n]);
      }
    }

    float linv = 1.f / l_r;
    float lnv[4];
#pragma unroll
    for (int r = 0; r < 4; ++r) lnv[r] = __shfl(linv, lg * 4 + r);
#pragma unroll
    for (int n = 0; n < 8; ++n)
#pragma unroll
      for (int r = 0; r < 4; ++r) {
        float val = o[n][r] * lnv[r];
        AttO[(rowb + q0 + wid * 16 + lg * 4 + r) * (size_t)(HH * 128) + h * 128 + n * 16 + lr] =
            f2bf(val);
      }
  }
}

// ---------- launch ----------
extern "C" void kernel_launch(void* const* d_in, const int* in_sizes, int n_in,
                              void* d_out, int out_size, void* d_ws, size_t ws_size,
                              hipStream_t stream) {
  const float* x       = (const float*)d_in[0];
  const float* wq_sem  = (const float*)d_in[1];
  const float* wk_sem  = (const float*)d_in[2];
  const float* wq_geo  = (const float*)d_in[3];
  const float* wk_geo  = (const float*)d_in[4];
  const float* wv      = (const float*)d_in[5];
  const float* wo      = (const float*)d_in[6];
  const float* gate    = (const float*)d_in[7];

  char* ws = (char*)d_ws;
  u16* Xbf   = (u16*)(ws);
  u16* WcatT = (u16*)(ws + 16777216);
  u16* WoT   = (u16*)(ws + 16777216 + 25165824);
  u16* P     = (u16*)(ws + 16777216 + 25165824 + 8388608);
  float* cosT = (float*)(ws + 16777216 + 25165824 + 8388608 + 50331648);
  float* sinT = cosT + 2048 * 32;
  u16* AttO = Xbf;    // Xbf dead after projection GEMM
  u16* VtG  = WcatT;  // WcatT dead after projection GEMM

  dim3 tb(32, 8);
  convert_bf16_k<<<8192, 256, 0, stream>>>(x, Xbf, (size_t)4096 * 2048);
  transpose_all_k<<<dim3(64, 64, 6), tb, 0, stream>>>(wq_sem, wk_sem, wq_geo, wk_geo,
                                                      wv, wo, WcatT, WoT);
  rope_table_k<<<256, 256, 0, stream>>>(cosT, sinT);

  // proj: BN=384 -> grid 16x32 = 512 blocks = 2 balanced rounds at 1 block/CU
  gemm4_k<6, false><<<dim3(16, 32), 256, 0, stream>>>(Xbf, WcatT, P, 4096, 6144, 2048);
  rope_apply_k<<<16384, 256, 0, stream>>>(P, cosT, sinT);
  vtrans_k<<<dim3(64, 64, 2), tb, 0, stream>>>(P, VtG);
  attn_k<<<dim3(256, 2), 256, 0, stream>>>(P, VtG, gate, AttO);
  // wo: BN=256 -> grid 8x32 = 256 blocks = 1 balanced round
  gemm4_k<4, true><<<dim3(8, 32), 256, 0, stream>>>(AttO, WoT, d_out, 4096, 2048, 2048);
}

// Round 13
// 258.666 us; speedup vs baseline: 1.0976x; 1.0148x over previous
//
#include <hip/hip_runtime.h>
#include <hip/hip_bf16.h>

typedef unsigned short u16;
typedef __attribute__((ext_vector_type(4))) float floatx4;
typedef __attribute__((ext_vector_type(8))) __bf16 bf16x8;

// ---------- helpers ----------
__device__ __forceinline__ u16 f2bf(float f) {
  unsigned int x = __builtin_bit_cast(unsigned int, f);
  unsigned int r = (x + 0x7fffu + ((x >> 16) & 1u)) >> 16;
  return (u16)r;
}
__device__ __forceinline__ float bf2f(u16 u) {
  unsigned int x = ((unsigned int)u) << 16;
  return __builtin_bit_cast(float, x);
}
__device__ __forceinline__ floatx4 mfma16(bf16x8 a, bf16x8 b, floatx4 c) {
  return __builtin_amdgcn_mfma_f32_16x16x32_bf16(a, b, c, 0, 0, 0);
}
__device__ __forceinline__ void gload16(const u16* g, u16* l) {
  __builtin_amdgcn_global_load_lds(
      (const __attribute__((address_space(1))) unsigned int*)g,
      (__attribute__((address_space(3))) unsigned int*)l, 16, 0, 0);
}
#define SCHEDB() __builtin_amdgcn_sched_barrier(0)
#define SBAR() __builtin_amdgcn_s_barrier()

// ---------- sizes ----------
#define BB 2
#define SS 2048
#define DM 2048
#define HH 16
#define PCOLS 6144   // qsem 1024 | ksem 1024 | qgeo 1024 | kgeo 1024 | v 2048

// ---------- fused prep kernel ----------
// z 0..5: weight transposes (dst[c][r] = bf16(src[r][c]), rows = 2048)
// z 6   : x -> bf16 (8.4M f32, 4096 blocks x 2048 elems)
// z 7   : rope cos/sin tables (65536 entries, first 256 blocks)
__global__ void prep_all_k(const float* __restrict__ x,
                           const float* w0, const float* w1, const float* w2,
                           const float* w3, const float* w4, const float* w5,
                           u16* __restrict__ WcatT, u16* __restrict__ WoT,
                           u16* __restrict__ Xbf,
                           float* __restrict__ cosT, float* __restrict__ sinT) {
  const int z = blockIdx.z;
  const int tx = threadIdx.x, ty = threadIdx.y;
  const int ftid = ty * 32 + tx;               // 0..255

  if (z == 6) {  // convert x -> bf16, 8 f32 per thread
    size_t base = ((size_t)(blockIdx.y * 64 + blockIdx.x)) * 2048 + (size_t)ftid * 8;
    float4 v0 = *(const float4*)&x[base];
    float4 v1 = *(const float4*)&x[base + 4];
    ushort4 o0, o1;
    o0.x = f2bf(v0.x); o0.y = f2bf(v0.y); o0.z = f2bf(v0.z); o0.w = f2bf(v0.w);
    o1.x = f2bf(v1.x); o1.y = f2bf(v1.y); o1.z = f2bf(v1.z); o1.w = f2bf(v1.w);
    *(ushort4*)&Xbf[base] = o0;
    *(ushort4*)&Xbf[base + 4] = o1;
    return;
  }
  if (z == 7) {  // rope tables
    int lb = blockIdx.y * 64 + blockIdx.x;
    if (lb >= 256) return;
    int idx = lb * 256 + ftid;                 // 0..65535 = 2048*32
    int s = idx >> 5, d = idx & 31;
    double inv = pow(10000.0, -(double)d / 32.0);
    double ang = (double)s * inv;
    cosT[idx] = (float)cos(ang);
    sinT[idx] = (float)sin(ang);
    return;
  }

  // z 0..5: weight transpose
  __shared__ float tile[32][33];
  const float* src; u16* dst; int cols;
  if (z == 0)      { src = w0; dst = WcatT;                        cols = 1024; }
  else if (z == 1) { src = w1; dst = WcatT + (size_t)1024 * 2048;  cols = 1024; }
  else if (z == 2) { src = w2; dst = WcatT + (size_t)2048 * 2048;  cols = 1024; }
  else if (z == 3) { src = w3; dst = WcatT + (size_t)3072 * 2048;  cols = 1024; }
  else if (z == 4) { src = w4; dst = WcatT + (size_t)4096 * 2048;  cols = 2048; }
  else             { src = w5; dst = WoT;                          cols = 2048; }
  int c0 = blockIdx.x * 32;
  if (c0 >= cols) return;
  int r0 = blockIdx.y * 32;
#pragma unroll
  for (int i = 0; i < 4; ++i)
    tile[ty + i * 8][tx] = src[(size_t)(r0 + ty + i * 8) * cols + c0 + tx];
  __syncthreads();
#pragma unroll
  for (int i = 0; i < 4; ++i)
    dst[(size_t)(c0 + ty + i * 8) * 2048 + r0 + tx] = f2bf(tile[tx][ty + i * 8]);
}

// ---------- fused rope_apply + V-transpose (disjoint P columns, safe concurrent) ----------
// blocks [0, 16384)      : in-place RoPE on P qgeo (cols 2048..3071) / kgeo (3072..4095)
// blocks [16384, 24576)  : V transpose P cols [4096..6144) -> VtG[(b*2048+h*128+dv)][s]
__global__ void ropevt_k(u16* __restrict__ P, const float* __restrict__ cosT,
                         const float* __restrict__ sinT, u16* __restrict__ VtG) {
  const int bid = blockIdx.x;
  const int tid = threadIdx.x;
  if (bid < 16384) {
    int idx = bid * 256 + tid;                  // rows(4096)*2*16*32
    int d = idx & 31, h = (idx >> 5) & 15, reg = (idx >> 9) & 1, row = idx >> 10;
    int s = row & (SS - 1);
    size_t base = (size_t)row * PCOLS + (reg ? 3072 : 2048) + h * 64 + d;
    float x1 = bf2f(P[base]), x2 = bf2f(P[base + 32]);
    float c = cosT[s * 32 + d], sn = sinT[s * 32 + d];
    P[base] = f2bf(x1 * c - x2 * sn);
    P[base + 32] = f2bf(x1 * sn + x2 * c);
    return;
  }
  // V transpose
  __shared__ u16 t[32][33];
  int b2 = bid - 16384;                         // 0..8191
  int b = b2 >> 12;                             // batch
  int s0 = ((b2 >> 6) & 63) * 32;
  int c0 = (b2 & 63) * 32;                      // combined (h,dv) index
  int tx = tid & 31, ty = tid >> 5;
#pragma unroll
  for (int i = 0; i < 4; ++i)
    t[ty + i * 8][tx] = P[((size_t)b * SS + s0 + ty + i * 8) * PCOLS + 4096 + c0 + tx];
  __syncthreads();
#pragma unroll
  for (int i = 0; i < 4; ++i)
    VtG[((size_t)b * 2048 + c0 + ty + i * 8) * SS + s0 + tx] = t[tx][ty + i * 8];
}

// ---------- 8-phase GEMM, 4 waves, big per-wave tile (116 µs proj champion) ----------
template <int NFB, bool OUTF32>
__global__ __launch_bounds__(256, 1)
void gemm4_k(const u16* __restrict__ A, const u16* __restrict__ Bt,
             void* __restrict__ Cout, int M, int N, int K) {
  constexpr int BH = NFB / 2;              // bfv frags per phase
  __shared__ alignas(16) u16 lds[16384 + NFB * 8192];
  const int tid = threadIdx.x;
  const int wid = tid >> 6, lane = tid & 63;
  const int lr = lane & 15, lg = lane >> 4;
  const int m0 = blockIdx.y * 128, n0 = blockIdx.x * (NFB * 64);
  const int NT = K >> 6;                   // K-tiles of 64
  const int NSLAB = NT * 4;

  const int aoff = lr * 32 + ((lg ^ ((lr >> 1) & 3)) * 8);

  const int srow = wid * 16 + (lane >> 2);
  const int sgl = (((lane & 3) ^ ((lane >> 3) & 3)) * 8);
  const u16* Asrc = A + (size_t)(m0 + srow) * K + sgl;
  const u16* Bsrc = Bt + (size_t)(n0 + srow) * K + sgl;

  floatx4 acc[8][NFB];
#pragma unroll
  for (int m = 0; m < 8; ++m)
#pragma unroll
    for (int n = 0; n < NFB; ++n) acc[m][n] = (floatx4){0.f, 0.f, 0.f, 0.f};

  auto stgA = [&](int tile, int kh) {
    u16* d = lds + ((tile & 1) * 2 + kh) * 4096 + wid * 512;
    const u16* s = Asrc + tile * 64 + kh * 32;
#pragma unroll
    for (int c = 0; c < 2; ++c) gload16(s + (size_t)(c * 64) * K, d + c * 2048);
  };
  auto stgB = [&](int tile, int kh) {
    u16* d = lds + 16384 + ((tile & 1) * 2 + kh) * (NFB * 2048) + wid * 512;
    const u16* s = Bsrc + tile * 64 + kh * 32;
#pragma unroll
    for (int c = 0; c < NFB; ++c) gload16(s + (size_t)(c * 64) * K, d + c * 2048);
  };
  auto stage_slab = [&](int s) {
    if (s >= NSLAB) return;
    int tile = s >> 2, kind = s & 3;
    if (kind == 0) stgA(tile, 0);
    else if (kind == 1) stgB(tile, 0);
    else if (kind == 2) stgA(tile, 1);
    else stgB(tile, 1);
  };

  for (int s = 0; s < 7; ++s) stage_slab(s);
  if constexpr (NFB == 6) asm volatile("s_waitcnt vmcnt(10)" ::: "memory");
  else                    asm volatile("s_waitcnt vmcnt(8)" ::: "memory");
  SCHEDB(); SBAR(); SCHEDB();

  bf16x8 af[8], bfv[BH];

#pragma unroll 1
  for (int it = 0; it < (NT >> 1); ++it) {
    const int t = it * 2;
    const int sb = t * 4 + 6;
    const bool more = (t + 2 < NT);

#define PH(BUF, KK, NH, SL, DOVM)                                               \
    {                                                                           \
      const u16* Ab = lds + ((BUF) * 2 + (KK)) * 4096;                          \
      const u16* Bb = lds + 16384 + ((BUF) * 2 + (KK)) * (NFB * 2048);          \
      if ((NH) == 0) {                                                          \
        _Pragma("unroll") for (int m = 0; m < 8; ++m)                           \
          af[m] = *(const bf16x8*)&Ab[(m * 16) * 32 + aoff];                    \
      }                                                                         \
      _Pragma("unroll") for (int j = 0; j < BH; ++j)                            \
        bfv[j] = *(const bf16x8*)&Bb[(wid * NFB * 16 + ((NH) * BH + j) * 16) * 32 + aoff]; \
      stage_slab(sb + (SL));                                                    \
      SCHEDB(); SBAR(); SCHEDB();                                               \
      __builtin_amdgcn_s_setprio(1);                                            \
      _Pragma("unroll") for (int m = 0; m < 8; ++m)                             \
        _Pragma("unroll") for (int j = 0; j < BH; ++j)                          \
          acc[m][(NH) * BH + j] = mfma16(af[m], bfv[j], acc[m][(NH) * BH + j]); \
      __builtin_amdgcn_s_setprio(0);                                            \
      if (DOVM) {                                                               \
        if (more) {                                                             \
          if constexpr (NFB == 6) asm volatile("s_waitcnt vmcnt(10)" ::: "memory"); \
          else                    asm volatile("s_waitcnt vmcnt(8)" ::: "memory");  \
        } else {                                                                \
          asm volatile("s_waitcnt vmcnt(0)" ::: "memory");                      \
        }                                                                       \
      }                                                                         \
      SCHEDB(); SBAR(); SCHEDB();                                               \
    }

    PH(0, 0, 0, 1, 0)
    PH(0, 0, 1, 2, 0)
    PH(0, 1, 0, 3, 0)
    PH(0, 1, 1, 4, 1)
    PH(1, 0, 0, 5, 0)
    PH(1, 0, 1, 6, 0)
    PH(1, 1, 0, 7, 0)
    PH(1, 1, 1, 8, 1)
#undef PH
  }

  // epilogue
#pragma unroll
  for (int m = 0; m < 8; ++m) {
    int row0 = m0 + m * 16 + lg * 4;
#pragma unroll
    for (int n = 0; n < NFB; ++n) {
      int col = n0 + wid * NFB * 16 + n * 16 + lr;
#pragma unroll
      for (int r = 0; r < 4; ++r) {
        size_t off = (size_t)(row0 + r) * N + col;
        if (OUTF32) ((float*)Cout)[off] = acc[m][n][r];
        else        ((u16*)Cout)[off] = f2bf(acc[m][n][r]);
      }
    }
  }
}

// ---------- flash attention: swapped QK^T, per-lane softmax, pair-balanced, defer-max ----------
__device__ __forceinline__ bf16x8 load_scaled(const u16* p, float s) {
  uint4 raw = *(const uint4*)p;
  const u16* ru = (const u16*)&raw;
  bf16x8 out;
#pragma unroll
  for (int j = 0; j < 8; ++j) out[j] = (__bf16)(bf2f(ru[j]) * s);
  return out;
}

__global__ __launch_bounds__(256, 3)
void attn_k(const u16* __restrict__ P, const u16* __restrict__ VtG,
            const float* __restrict__ gate, u16* __restrict__ AttO) {
  // grid: x = 256 (pair 0..15 x 16 heads), y = B. Block does q-tiles pairi and 31-pairi
  // (64 rows each): (pairi+1) + (32-pairi) = 33 kv-iterations per block — perfect balance.
  const int pairi = blockIdx.x >> 4;
  const int h = blockIdx.x & 15;
  const int b = blockIdx.y;
  const int tid = threadIdx.x, wid = tid >> 6, lane = tid & 63;
  const int lr = lane & 15, lg = lane >> 4;
  const size_t rowb = (size_t)b * SS;

  const float g = 1.f / (1.f + __expf(-gate[h]));
  const float ssc = g * 0.125f;          // g / sqrt(DS)
  const float gsc = (1.f - g) * 0.125f;  // (1-g) / sqrt(DG)

  // all tiles [rows][64] linear, granule-swizzled: byte ^= (row&7)<<4
  __shared__ alignas(16) u16 Ks[64 * 64];
  __shared__ alignas(16) u16 Kg[64 * 64];
  __shared__ alignas(16) u16 Vt[128 * 64];
  __shared__ alignas(16) u16 Pw[4][16 * 64];

  const int strow = tid >> 3;                 // 0..31
  const int stg = ((tid & 7) ^ (strow & 7)) * 8;
  const int swz = lr & 7;                     // read-side swizzle (row&7 == lr&7)

  for (int half = 0; half < 2; ++half) {
    const int qb = half ? (31 - pairi) : pairi;
    const int q0 = qb * 64;

    // Q fragments (B-operand: lane holds Q[q = q0+wid*16+lr][k = kk*32+lg*8..+7])
    const u16* qbase = P + (rowb + q0 + wid * 16 + lr) * PCOLS + h * 64;
    bf16x8 qs[2], qg[2];
#pragma unroll
    for (int kk = 0; kk < 2; ++kk) {
      qs[kk] = load_scaled(qbase + kk * 32 + lg * 8, ssc);
      qg[kk] = load_scaled(qbase + 2048 + kk * 32 + lg * 8, gsc);
    }

    float m_r = -1e30f, l_r = 0.f;
    floatx4 o[8];
#pragma unroll
    for (int n = 0; n < 8; ++n) o[n] = (floatx4){0.f, 0.f, 0.f, 0.f};

    const int nkv = q0 + 64;
    for (int kv0 = 0; kv0 < nkv; kv0 += 64) {
      __syncthreads();
      {  // stage K_sem/K_geo rows 0..63 via global_load_lds (linear dest, pre-swizzled src)
        const u16* ks = P + (rowb + kv0 + strow) * PCOLS + 1024 + h * 64 + stg;
        const u16* gs = P + (rowb + kv0 + strow) * PCOLS + 3072 + h * 64 + stg;
        gload16(ks, Ks + wid * 512);
        gload16(gs, Kg + wid * 512);
        gload16(ks + (size_t)32 * PCOLS, Ks + 2048 + wid * 512);
        gload16(gs + (size_t)32 * PCOLS, Kg + 2048 + wid * 512);
      }
      {  // stage V^T rows (dv) 0..127
        const u16* vs = VtG + ((size_t)b * 2048 + h * 128 + strow) * SS + kv0 + stg;
#pragma unroll
        for (int c = 0; c < 4; ++c)
          gload16(vs + (size_t)(c * 32) * SS, Vt + c * 2048 + wid * 512);
      }
      __syncthreads();   // compiler drains vmcnt before barrier

      // swapped QK^T: lane holds score(q=q0+wid*16+lr, k=kv0+s*16+lg*4+r)
      floatx4 sc[4];
#pragma unroll
      for (int s = 0; s < 4; ++s) sc[s] = (floatx4){0.f, 0.f, 0.f, 0.f};
#pragma unroll
      for (int kk = 0; kk < 2; ++kk) {
#pragma unroll
        for (int s = 0; s < 4; ++s) {
          bf16x8 kf = *(const bf16x8*)&Ks[(s * 16 + lr) * 64 + ((kk * 4 + lg) ^ swz) * 8];
          bf16x8 gf = *(const bf16x8*)&Kg[(s * 16 + lr) * 64 + ((kk * 4 + lg) ^ swz) * 8];
          sc[s] = mfma16(kf, qs[kk], sc[s]);
          sc[s] = mfma16(gf, qg[kk], sc[s]);
        }
      }

      // per-lane softmax over this lane's 16 values (its q-row = lr)
      const int qrow = q0 + wid * 16 + lr;
      const bool needmask = (kv0 + 63 > q0 + wid * 16);
      float vv[4][4];
      float vmax = -1e30f;
#pragma unroll
      for (int s = 0; s < 4; ++s)
#pragma unroll
        for (int r = 0; r < 4; ++r) {
          float val = sc[s][r];
          if (needmask) val = (kv0 + s * 16 + lg * 4 + r <= qrow) ? val : -1e30f;
          vv[s][r] = val;
          vmax = fmaxf(vmax, val);
        }
      vmax = fmaxf(vmax, __shfl_xor(vmax, 16));
      vmax = fmaxf(vmax, __shfl_xor(vmax, 32));

      // T13 defer-max: if row max grew by <= 8 for ALL rows of this wave, keep m_r
      // (P bounded by e^8 — same relative bf16 precision) and skip the O-rescale.
      const bool defer = __all(vmax - m_r <= 8.0f);
      const float mnew = defer ? m_r : fmaxf(m_r, vmax);
      float psum = 0.f;
#pragma unroll
      for (int s = 0; s < 4; ++s)
#pragma unroll
        for (int r = 0; r < 4; ++r) {
          vv[s][r] = __expf(vv[s][r] - mnew);
          psum += vv[s][r];
        }
      psum += __shfl_xor(psum, 16);
      psum += __shfl_xor(psum, 32);

      // pack P to bf16 pairs, write swizzled: value k=s*16+lg*4+2t(,+1) at row lr
#pragma unroll
      for (int s = 0; s < 4; ++s)
#pragma unroll
        for (int t = 0; t < 2; ++t) {
          unsigned int w;
          asm("v_cvt_pk_bf16_f32 %0, %1, %2" : "=v"(w) : "v"(vv[s][2 * t]), "v"(vv[s][2 * t + 1]));
          int u16off = lr * 64 + ((s * 2 + (lg >> 1)) ^ swz) * 8 + (lg & 1) * 4 + t * 2;
          *(unsigned int*)&Pw[wid][u16off] = w;
        }

      // rescale (skipped when deferred) — VALU here overlaps the Pw ds_write latency
      if (!defer) {
        float corr = __expf(m_r - mnew);
        l_r *= corr;
        m_r = mnew;
        float crr[4];
#pragma unroll
        for (int r = 0; r < 4; ++r) crr[r] = __shfl(corr, lg * 4 + r);
#pragma unroll
        for (int n = 0; n < 8; ++n)
#pragma unroll
          for (int r = 0; r < 4; ++r) o[n][r] *= crr[r];
      }
      l_r += psum;

      asm volatile("s_waitcnt lgkmcnt(0)" ::: "memory");
      SCHEDB();
      // PV: A = P[q=lr][k-chunk], B = Vt[dv=n*16+lr][k-chunk]
      bf16x8 pa0 = *(const bf16x8*)&Pw[wid][lr * 64 + (lg ^ swz) * 8];
      bf16x8 pa1 = *(const bf16x8*)&Pw[wid][lr * 64 + ((4 + lg) ^ swz) * 8];
#pragma unroll
      for (int n = 0; n < 8; ++n) {
        bf16x8 vb0 = *(const bf16x8*)&Vt[(n * 16 + lr) * 64 + (lg ^ swz) * 8];
        bf16x8 vb1 = *(const bf16x8*)&Vt[(n * 16 + lr) * 64 + ((4 + lg) ^ swz) * 8];
        o[n] = mfma16(pa0, vb0, o[n]);
        o[n] = mfma16(pa1, vb1, o[n]);
      }
    }

    float linv = 1.f / l_r;
    float lnv[4];
#pragma unroll
    for (int r = 0; r < 4; ++r) lnv[r] = __shfl(linv, lg * 4 + r);
#pragma unroll
    for (int n = 0; n < 8; ++n)
#pragma unroll
      for (int r = 0; r < 4; ++r) {
        float val = o[n][r] * lnv[r];
        AttO[(rowb + q0 + wid * 16 + lg * 4 + r) * (size_t)(HH * 128) + h * 128 + n * 16 + lr] =
            f2bf(val);
      }
  }
}

// ---------- launch ----------
extern "C" void kernel_launch(void* const* d_in, const int* in_sizes, int n_in,
                              void* d_out, int out_size, void* d_ws, size_t ws_size,
                              hipStream_t stream) {
  const float* x       = (const float*)d_in[0];
  const float* wq_sem  = (const float*)d_in[1];
  const float* wk_sem  = (const float*)d_in[2];
  const float* wq_geo  = (const float*)d_in[3];
  const float* wk_geo  = (const float*)d_in[4];
  const float* wv      = (const float*)d_in[5];
  const float* wo      = (const float*)d_in[6];
  const float* gate    = (const float*)d_in[7];

  char* ws = (char*)d_ws;
  u16* Xbf   = (u16*)(ws);
  u16* WcatT = (u16*)(ws + 16777216);
  u16* WoT   = (u16*)(ws + 16777216 + 25165824);
  u16* P     = (u16*)(ws + 16777216 + 25165824 + 8388608);
  float* cosT = (float*)(ws + 16777216 + 25165824 + 8388608 + 50331648);
  float* sinT = cosT + 2048 * 32;
  u16* AttO = Xbf;    // Xbf dead after projection GEMM
  u16* VtG  = WcatT;  // WcatT dead after projection GEMM

  dim3 tb(32, 8);
  prep_all_k<<<dim3(64, 64, 8), tb, 0, stream>>>(x, wq_sem, wk_sem, wq_geo, wk_geo,
                                                 wv, wo, WcatT, WoT, Xbf, cosT, sinT);

  // proj: BN=384 -> grid 16x32 = 512 blocks = 2 balanced rounds at 1 block/CU
  gemm4_k<6, false><<<dim3(16, 32), 256, 0, stream>>>(Xbf, WcatT, P, 4096, 6144, 2048);
  // fused RoPE (blocks 0..16383) + V-transpose (blocks 16384..24575)
  ropevt_k<<<24576, 256, 0, stream>>>(P, cosT, sinT, VtG);
  attn_k<<<dim3(256, 2), 256, 0, stream>>>(P, VtG, gate, AttO);
  // wo: BN=256 -> grid 8x32 = 256 blocks = 1 balanced round
  gemm4_k<4, true><<<dim3(8, 32), 256, 0, stream>>>(AttO, WoT, d_out, 4096, 2048, 2048);
}

// Round 14
// 255.192 us; speedup vs baseline: 1.1126x; 1.0136x over previous
//
#include <hip/hip_runtime.h>
#include <hip/hip_bf16.h>

typedef unsigned short u16;
typedef __attribute__((ext_vector_type(4))) float floatx4;
typedef __attribute__((ext_vector_type(8))) __bf16 bf16x8;

// ---------- helpers ----------
__device__ __forceinline__ u16 f2bf(float f) {
  unsigned int x = __builtin_bit_cast(unsigned int, f);
  unsigned int r = (x + 0x7fffu + ((x >> 16) & 1u)) >> 16;
  return (u16)r;
}
__device__ __forceinline__ float bf2f(u16 u) {
  unsigned int x = ((unsigned int)u) << 16;
  return __builtin_bit_cast(float, x);
}
__device__ __forceinline__ floatx4 mfma16(bf16x8 a, bf16x8 b, floatx4 c) {
  return __builtin_amdgcn_mfma_f32_16x16x32_bf16(a, b, c, 0, 0, 0);
}
__device__ __forceinline__ void gload16(const u16* g, u16* l) {
  __builtin_amdgcn_global_load_lds(
      (const __attribute__((address_space(1))) unsigned int*)g,
      (__attribute__((address_space(3))) unsigned int*)l, 16, 0, 0);
}
#define SCHEDB() __builtin_amdgcn_sched_barrier(0)
#define SBAR() __builtin_amdgcn_s_barrier()

// ---------- sizes ----------
#define BB 2
#define SS 2048
#define DM 2048
#define HH 16
#define PCOLS 6144   // qsem 1024 | ksem 1024 | qgeo 1024 | kgeo 1024 | v 2048

// ---------- fused prep kernel ----------
// z 0..5: weight transposes (dst[c][r] = bf16(src[r][c]), rows = 2048)
// z 6   : x -> bf16 (8.4M f32, 4096 blocks x 2048 elems)
// z 7   : rope cos/sin tables (65536 entries, first 256 blocks)
__global__ void prep_all_k(const float* __restrict__ x,
                           const float* w0, const float* w1, const float* w2,
                           const float* w3, const float* w4, const float* w5,
                           u16* __restrict__ WcatT, u16* __restrict__ WoT,
                           u16* __restrict__ Xbf,
                           float* __restrict__ cosT, float* __restrict__ sinT) {
  const int z = blockIdx.z;
  const int tx = threadIdx.x, ty = threadIdx.y;
  const int ftid = ty * 32 + tx;               // 0..255

  if (z == 6) {  // convert x -> bf16, 8 f32 per thread
    size_t base = ((size_t)(blockIdx.y * 64 + blockIdx.x)) * 2048 + (size_t)ftid * 8;
    float4 v0 = *(const float4*)&x[base];
    float4 v1 = *(const float4*)&x[base + 4];
    ushort4 o0, o1;
    o0.x = f2bf(v0.x); o0.y = f2bf(v0.y); o0.z = f2bf(v0.z); o0.w = f2bf(v0.w);
    o1.x = f2bf(v1.x); o1.y = f2bf(v1.y); o1.z = f2bf(v1.z); o1.w = f2bf(v1.w);
    *(ushort4*)&Xbf[base] = o0;
    *(ushort4*)&Xbf[base + 4] = o1;
    return;
  }
  if (z == 7) {  // rope tables
    int lb = blockIdx.y * 64 + blockIdx.x;
    if (lb >= 256) return;
    int idx = lb * 256 + ftid;                 // 0..65535 = 2048*32
    int s = idx >> 5, d = idx & 31;
    double inv = pow(10000.0, -(double)d / 32.0);
    double ang = (double)s * inv;
    cosT[idx] = (float)cos(ang);
    sinT[idx] = (float)sin(ang);
    return;
  }

  // z 0..5: weight transpose
  __shared__ float tile[32][33];
  const float* src; u16* dst; int cols;
  if (z == 0)      { src = w0; dst = WcatT;                        cols = 1024; }
  else if (z == 1) { src = w1; dst = WcatT + (size_t)1024 * 2048;  cols = 1024; }
  else if (z == 2) { src = w2; dst = WcatT + (size_t)2048 * 2048;  cols = 1024; }
  else if (z == 3) { src = w3; dst = WcatT + (size_t)3072 * 2048;  cols = 1024; }
  else if (z == 4) { src = w4; dst = WcatT + (size_t)4096 * 2048;  cols = 2048; }
  else             { src = w5; dst = WoT;                          cols = 2048; }
  int c0 = blockIdx.x * 32;
  if (c0 >= cols) return;
  int r0 = blockIdx.y * 32;
#pragma unroll
  for (int i = 0; i < 4; ++i)
    tile[ty + i * 8][tx] = src[(size_t)(r0 + ty + i * 8) * cols + c0 + tx];
  __syncthreads();
#pragma unroll
  for (int i = 0; i < 4; ++i)
    dst[(size_t)(c0 + ty + i * 8) * 2048 + r0 + tx] = f2bf(tile[tx][ty + i * 8]);
}

// ---------- fused vectorized rope_apply + V-transpose ----------
// blocks [0, 2048)      : in-place RoPE on P qgeo/kgeo, 8 d-values per thread (16B loads)
// blocks [2048, 10240)  : V transpose P cols [4096..6144) -> VtG[(b*2048+h*128+dv)][s]
__global__ void ropevt_k(u16* __restrict__ P, const float* __restrict__ cosT,
                         const float* __restrict__ sinT, u16* __restrict__ VtG) {
  const int bid = blockIdx.x;
  const int tid = threadIdx.x;
  if (bid < 2048) {
    int idx = bid * 256 + tid;                  // 0..524287 = rows(4096)*2*16*4
    int d0 = (idx & 3) * 8;                     // 0,8,16,24
    int h = (idx >> 2) & 15, reg = (idx >> 6) & 1, row = idx >> 7;
    int s = row & (SS - 1);
    size_t base = (size_t)row * PCOLS + (reg ? 3072 : 2048) + h * 64 + d0;
    ushort4 x1a = *(const ushort4*)&P[base];
    ushort4 x1b = *(const ushort4*)&P[base + 4];
    ushort4 x2a = *(const ushort4*)&P[base + 32];
    ushort4 x2b = *(const ushort4*)&P[base + 36];
    float4 ca = *(const float4*)&cosT[s * 32 + d0];
    float4 cb = *(const float4*)&cosT[s * 32 + d0 + 4];
    float4 sa = *(const float4*)&sinT[s * 32 + d0];
    float4 sb = *(const float4*)&sinT[s * 32 + d0 + 4];
    const u16* x1 = (const u16*)&x1a;   // x1a,x1b contiguous? use arrays instead
    u16 x1v[8] = {x1a.x, x1a.y, x1a.z, x1a.w, x1b.x, x1b.y, x1b.z, x1b.w};
    u16 x2v[8] = {x2a.x, x2a.y, x2a.z, x2a.w, x2b.x, x2b.y, x2b.z, x2b.w};
    float cv[8] = {ca.x, ca.y, ca.z, ca.w, cb.x, cb.y, cb.z, cb.w};
    float sv[8] = {sa.x, sa.y, sa.z, sa.w, sb.x, sb.y, sb.z, sb.w};
    ushort4 o1a, o1b, o2a, o2b;
    u16* o1 = (u16*)&o1a;  // o1a,o1b as array of 8
    u16 o1v[8], o2v[8];
#pragma unroll
    for (int j = 0; j < 8; ++j) {
      float a1 = bf2f(x1v[j]), a2 = bf2f(x2v[j]);
      o1v[j] = f2bf(a1 * cv[j] - a2 * sv[j]);
      o2v[j] = f2bf(a1 * sv[j] + a2 * cv[j]);
    }
    o1a.x = o1v[0]; o1a.y = o1v[1]; o1a.z = o1v[2]; o1a.w = o1v[3];
    o1b.x = o1v[4]; o1b.y = o1v[5]; o1b.z = o1v[6]; o1b.w = o1v[7];
    o2a.x = o2v[0]; o2a.y = o2v[1]; o2a.z = o2v[2]; o2a.w = o2v[3];
    o2b.x = o2v[4]; o2b.y = o2v[5]; o2b.z = o2v[6]; o2b.w = o2v[7];
    *(ushort4*)&P[base] = o1a;
    *(ushort4*)&P[base + 4] = o1b;
    *(ushort4*)&P[base + 32] = o2a;
    *(ushort4*)&P[base + 36] = o2b;
    (void)x1; (void)o1;
    return;
  }
  // V transpose
  __shared__ u16 t[32][33];
  int b2 = bid - 2048;                          // 0..8191
  int b = b2 >> 12;                             // batch
  int s0 = ((b2 >> 6) & 63) * 32;
  int c0 = (b2 & 63) * 32;                      // combined (h,dv) index
  int tx = tid & 31, ty = tid >> 5;
#pragma unroll
  for (int i = 0; i < 4; ++i)
    t[ty + i * 8][tx] = P[((size_t)b * SS + s0 + ty + i * 8) * PCOLS + 4096 + c0 + tx];
  __syncthreads();
#pragma unroll
  for (int i = 0; i < 4; ++i)
    VtG[((size_t)b * 2048 + c0 + ty + i * 8) * SS + s0 + tx] = t[tx][ty + i * 8];
}

// ---------- 8-phase GEMM, 4 waves, big per-wave tile (116 µs proj champion) ----------
template <int NFB, bool OUTF32>
__global__ __launch_bounds__(256, 1)
void gemm4_k(const u16* __restrict__ A, const u16* __restrict__ Bt,
             void* __restrict__ Cout, int M, int N, int K) {
  constexpr int BH = NFB / 2;              // bfv frags per phase
  __shared__ alignas(16) u16 lds[16384 + NFB * 8192];
  const int tid = threadIdx.x;
  const int wid = tid >> 6, lane = tid & 63;
  const int lr = lane & 15, lg = lane >> 4;
  const int m0 = blockIdx.y * 128, n0 = blockIdx.x * (NFB * 64);
  const int NT = K >> 6;                   // K-tiles of 64
  const int NSLAB = NT * 4;

  const int aoff = lr * 32 + ((lg ^ ((lr >> 1) & 3)) * 8);

  const int srow = wid * 16 + (lane >> 2);
  const int sgl = (((lane & 3) ^ ((lane >> 3) & 3)) * 8);
  const u16* Asrc = A + (size_t)(m0 + srow) * K + sgl;
  const u16* Bsrc = Bt + (size_t)(n0 + srow) * K + sgl;

  floatx4 acc[8][NFB];
#pragma unroll
  for (int m = 0; m < 8; ++m)
#pragma unroll
    for (int n = 0; n < NFB; ++n) acc[m][n] = (floatx4){0.f, 0.f, 0.f, 0.f};

  auto stgA = [&](int tile, int kh) {
    u16* d = lds + ((tile & 1) * 2 + kh) * 4096 + wid * 512;
    const u16* s = Asrc + tile * 64 + kh * 32;
#pragma unroll
    for (int c = 0; c < 2; ++c) gload16(s + (size_t)(c * 64) * K, d + c * 2048);
  };
  auto stgB = [&](int tile, int kh) {
    u16* d = lds + 16384 + ((tile & 1) * 2 + kh) * (NFB * 2048) + wid * 512;
    const u16* s = Bsrc + tile * 64 + kh * 32;
#pragma unroll
    for (int c = 0; c < NFB; ++c) gload16(s + (size_t)(c * 64) * K, d + c * 2048);
  };
  auto stage_slab = [&](int s) {
    if (s >= NSLAB) return;
    int tile = s >> 2, kind = s & 3;
    if (kind == 0) stgA(tile, 0);
    else if (kind == 1) stgB(tile, 0);
    else if (kind == 2) stgA(tile, 1);
    else stgB(tile, 1);
  };

  for (int s = 0; s < 7; ++s) stage_slab(s);
  if constexpr (NFB == 6) asm volatile("s_waitcnt vmcnt(10)" ::: "memory");
  else                    asm volatile("s_waitcnt vmcnt(8)" ::: "memory");
  SCHEDB(); SBAR(); SCHEDB();

  bf16x8 af[8], bfv[BH];

#pragma unroll 1
  for (int it = 0; it < (NT >> 1); ++it) {
    const int t = it * 2;
    const int sb = t * 4 + 6;
    const bool more = (t + 2 < NT);

#define PH(BUF, KK, NH, SL, DOVM)                                               \
    {                                                                           \
      const u16* Ab = lds + ((BUF) * 2 + (KK)) * 4096;                          \
      const u16* Bb = lds + 16384 + ((BUF) * 2 + (KK)) * (NFB * 2048);          \
      if ((NH) == 0) {                                                          \
        _Pragma("unroll") for (int m = 0; m < 8; ++m)                           \
          af[m] = *(const bf16x8*)&Ab[(m * 16) * 32 + aoff];                    \
      }                                                                         \
      _Pragma("unroll") for (int j = 0; j < BH; ++j)                            \
        bfv[j] = *(const bf16x8*)&Bb[(wid * NFB * 16 + ((NH) * BH + j) * 16) * 32 + aoff]; \
      stage_slab(sb + (SL));                                                    \
      SCHEDB(); SBAR(); SCHEDB();                                               \
      __builtin_amdgcn_s_setprio(1);                                            \
      _Pragma("unroll") for (int m = 0; m < 8; ++m)                             \
        _Pragma("unroll") for (int j = 0; j < BH; ++j)                          \
          acc[m][(NH) * BH + j] = mfma16(af[m], bfv[j], acc[m][(NH) * BH + j]); \
      __builtin_amdgcn_s_setprio(0);                                            \
      if (DOVM) {                                                               \
        if (more) {                                                             \
          if constexpr (NFB == 6) asm volatile("s_waitcnt vmcnt(10)" ::: "memory"); \
          else                    asm volatile("s_waitcnt vmcnt(8)" ::: "memory");  \
        } else {                                                                \
          asm volatile("s_waitcnt vmcnt(0)" ::: "memory");                      \
        }                                                                       \
      }                                                                         \
      SCHEDB(); SBAR(); SCHEDB();                                               \
    }

    PH(0, 0, 0, 1, 0)
    PH(0, 0, 1, 2, 0)
    PH(0, 1, 0, 3, 0)
    PH(0, 1, 1, 4, 1)
    PH(1, 0, 0, 5, 0)
    PH(1, 0, 1, 6, 0)
    PH(1, 1, 0, 7, 0)
    PH(1, 1, 1, 8, 1)
#undef PH
  }

  // epilogue
#pragma unroll
  for (int m = 0; m < 8; ++m) {
    int row0 = m0 + m * 16 + lg * 4;
#pragma unroll
    for (int n = 0; n < NFB; ++n) {
      int col = n0 + wid * NFB * 16 + n * 16 + lr;
#pragma unroll
      for (int r = 0; r < 4; ++r) {
        size_t off = (size_t)(row0 + r) * N + col;
        if (OUTF32) ((float*)Cout)[off] = acc[m][n][r];
        else        ((u16*)Cout)[off] = f2bf(acc[m][n][r]);
      }
    }
  }
}

// ---------- flash attention: swapped QK^T, per-lane softmax, pair-balanced, defer-max ----------
__device__ __forceinline__ bf16x8 load_scaled(const u16* p, float s) {
  uint4 raw = *(const uint4*)p;
  const u16* ru = (const u16*)&raw;
  bf16x8 out;
#pragma unroll
  for (int j = 0; j < 8; ++j) out[j] = (__bf16)(bf2f(ru[j]) * s);
  return out;
}

__global__ __launch_bounds__(256, 3)
void attn_k(const u16* __restrict__ P, const u16* __restrict__ VtG,
            const float* __restrict__ gate, u16* __restrict__ AttO) {
  // grid: x = 256 (pair 0..15 x 16 heads), y = B. Block does q-tiles pairi and 31-pairi
  // (64 rows each): (pairi+1) + (32-pairi) = 33 kv-iterations per block — perfect balance.
  const int pairi = blockIdx.x >> 4;
  const int h = blockIdx.x & 15;
  const int b = blockIdx.y;
  const int tid = threadIdx.x, wid = tid >> 6, lane = tid & 63;
  const int lr = lane & 15, lg = lane >> 4;
  const size_t rowb = (size_t)b * SS;

  const float g = 1.f / (1.f + __expf(-gate[h]));
  const float ssc = g * 0.125f;          // g / sqrt(DS)
  const float gsc = (1.f - g) * 0.125f;  // (1-g) / sqrt(DG)

  // all tiles [rows][64] linear, granule-swizzled: byte ^= (row&7)<<4
  __shared__ alignas(16) u16 Ks[64 * 64];
  __shared__ alignas(16) u16 Kg[64 * 64];
  __shared__ alignas(16) u16 Vt[128 * 64];
  __shared__ alignas(16) u16 Pw[4][16 * 64];

  const int strow = tid >> 3;                 // 0..31
  const int stg = ((tid & 7) ^ (strow & 7)) * 8;
  const int swz = lr & 7;                     // read-side swizzle (row&7 == lr&7)

  for (int half = 0; half < 2; ++half) {
    const int qb = half ? (31 - pairi) : pairi;
    const int q0 = qb * 64;

    // Q fragments (B-operand: lane holds Q[q = q0+wid*16+lr][k = kk*32+lg*8..+7])
    const u16* qbase = P + (rowb + q0 + wid * 16 + lr) * PCOLS + h * 64;
    bf16x8 qs[2], qg[2];
#pragma unroll
    for (int kk = 0; kk < 2; ++kk) {
      qs[kk] = load_scaled(qbase + kk * 32 + lg * 8, ssc);
      qg[kk] = load_scaled(qbase + 2048 + kk * 32 + lg * 8, gsc);
    }

    float m_r = -1e30f, l_r = 0.f;
    floatx4 o[8];
#pragma unroll
    for (int n = 0; n < 8; ++n) o[n] = (floatx4){0.f, 0.f, 0.f, 0.f};

    const int nkv = q0 + 64;
    for (int kv0 = 0; kv0 < nkv; kv0 += 64) {
      __syncthreads();
      {  // stage K_sem/K_geo rows 0..63 via global_load_lds (linear dest, pre-swizzled src)
        const u16* ks = P + (rowb + kv0 + strow) * PCOLS + 1024 + h * 64 + stg;
        const u16* gs = P + (rowb + kv0 + strow) * PCOLS + 3072 + h * 64 + stg;
        gload16(ks, Ks + wid * 512);
        gload16(gs, Kg + wid * 512);
        gload16(ks + (size_t)32 * PCOLS, Ks + 2048 + wid * 512);
        gload16(gs + (size_t)32 * PCOLS, Kg + 2048 + wid * 512);
      }
      {  // stage V^T rows (dv) 0..127
        const u16* vs = VtG + ((size_t)b * 2048 + h * 128 + strow) * SS + kv0 + stg;
#pragma unroll
        for (int c = 0; c < 4; ++c)
          gload16(vs + (size_t)(c * 32) * SS, Vt + c * 2048 + wid * 512);
      }
      __syncthreads();   // compiler drains vmcnt before barrier

      // swapped QK^T: lane holds score(q=q0+wid*16+lr, k=kv0+s*16+lg*4+r)
      floatx4 sc[4];
#pragma unroll
      for (int s = 0; s < 4; ++s) sc[s] = (floatx4){0.f, 0.f, 0.f, 0.f};
      __builtin_amdgcn_s_setprio(1);
#pragma unroll
      for (int kk = 0; kk < 2; ++kk) {
#pragma unroll
        for (int s = 0; s < 4; ++s) {
          bf16x8 kf = *(const bf16x8*)&Ks[(s * 16 + lr) * 64 + ((kk * 4 + lg) ^ swz) * 8];
          bf16x8 gf = *(const bf16x8*)&Kg[(s * 16 + lr) * 64 + ((kk * 4 + lg) ^ swz) * 8];
          sc[s] = mfma16(kf, qs[kk], sc[s]);
          sc[s] = mfma16(gf, qg[kk], sc[s]);
        }
      }
      __builtin_amdgcn_s_setprio(0);

      // per-lane softmax over this lane's 16 values (its q-row = lr)
      const int qrow = q0 + wid * 16 + lr;
      const bool needmask = (kv0 + 63 > q0 + wid * 16);
      float vv[4][4];
      float vmax = -1e30f;
#pragma unroll
      for (int s = 0; s < 4; ++s)
#pragma unroll
        for (int r = 0; r < 4; ++r) {
          float val = sc[s][r];
          if (needmask) val = (kv0 + s * 16 + lg * 4 + r <= qrow) ? val : -1e30f;
          vv[s][r] = val;
          vmax = fmaxf(vmax, val);
        }
      vmax = fmaxf(vmax, __shfl_xor(vmax, 16));
      vmax = fmaxf(vmax, __shfl_xor(vmax, 32));

      // T13 defer-max: if row max grew by <= 8 for ALL rows of this wave, keep m_r
      // (P bounded by e^8 — same relative bf16 precision) and skip the O-rescale.
      const bool defer = __all(vmax - m_r <= 8.0f);
      const float mnew = defer ? m_r : fmaxf(m_r, vmax);
      float psum = 0.f;
#pragma unroll
      for (int s = 0; s < 4; ++s)
#pragma unroll
        for (int r = 0; r < 4; ++r) {
          vv[s][r] = __expf(vv[s][r] - mnew);
          psum += vv[s][r];
        }
      psum += __shfl_xor(psum, 16);
      psum += __shfl_xor(psum, 32);

      // pack P to bf16 pairs, write swizzled: value k=s*16+lg*4+2t(,+1) at row lr
#pragma unroll
      for (int s = 0; s < 4; ++s)
#pragma unroll
        for (int t = 0; t < 2; ++t) {
          unsigned int w;
          asm("v_cvt_pk_bf16_f32 %0, %1, %2" : "=v"(w) : "v"(vv[s][2 * t]), "v"(vv[s][2 * t + 1]));
          int u16off = lr * 64 + ((s * 2 + (lg >> 1)) ^ swz) * 8 + (lg & 1) * 4 + t * 2;
          *(unsigned int*)&Pw[wid][u16off] = w;
        }

      // rescale (skipped when deferred) — VALU here overlaps the Pw ds_write latency
      if (!defer) {
        float corr = __expf(m_r - mnew);
        l_r *= corr;
        m_r = mnew;
        float crr[4];
#pragma unroll
        for (int r = 0; r < 4; ++r) crr[r] = __shfl(corr, lg * 4 + r);
#pragma unroll
        for (int n = 0; n < 8; ++n)
#pragma unroll
          for (int r = 0; r < 4; ++r) o[n][r] *= crr[r];
      }
      l_r += psum;

      asm volatile("s_waitcnt lgkmcnt(0)" ::: "memory");
      SCHEDB();
      // PV: A = P[q=lr][k-chunk], B = Vt[dv=n*16+lr][k-chunk]
      bf16x8 pa0 = *(const bf16x8*)&Pw[wid][lr * 64 + (lg ^ swz) * 8];
      bf16x8 pa1 = *(const bf16x8*)&Pw[wid][lr * 64 + ((4 + lg) ^ swz) * 8];
      __builtin_amdgcn_s_setprio(1);
#pragma unroll
      for (int n = 0; n < 8; ++n) {
        bf16x8 vb0 = *(const bf16x8*)&Vt[(n * 16 + lr) * 64 + (lg ^ swz) * 8];
        bf16x8 vb1 = *(const bf16x8*)&Vt[(n * 16 + lr) * 64 + ((4 + lg) ^ swz) * 8];
        o[n] = mfma16(pa0, vb0, o[n]);
        o[n] = mfma16(pa1, vb1, o[n]);
      }
      __builtin_amdgcn_s_setprio(0);
    }

    float linv = 1.f / l_r;
    float lnv[4];
#pragma unroll
    for (int r = 0; r < 4; ++r) lnv[r] = __shfl(linv, lg * 4 + r);
#pragma unroll
    for (int n = 0; n < 8; ++n)
#pragma unroll
      for (int r = 0; r < 4; ++r) {
        float val = o[n][r] * lnv[r];
        AttO[(rowb + q0 + wid * 16 + lg * 4 + r) * (size_t)(HH * 128) + h * 128 + n * 16 + lr] =
            f2bf(val);
      }
  }
}

// ---------- launch ----------
extern "C" void kernel_launch(void* const* d_in, const int* in_sizes, int n_in,
                              void* d_out, int out_size, void* d_ws, size_t ws_size,
                              hipStream_t stream) {
  const float* x       = (const float*)d_in[0];
  const float* wq_sem  = (const float*)d_in[1];
  const float* wk_sem  = (const float*)d_in[2];
  const float* wq_geo  = (const float*)d_in[3];
  const float* wk_geo  = (const float*)d_in[4];
  const float* wv      = (const float*)d_in[5];
  const float* wo      = (const float*)d_in[6];
  const float* gate    = (const float*)d_in[7];

  char* ws = (char*)d_ws;
  u16* Xbf   = (u16*)(ws);
  u16* WcatT = (u16*)(ws + 16777216);
  u16* WoT   = (u16*)(ws + 16777216 + 25165824);
  u16* P     = (u16*)(ws + 16777216 + 25165824 + 8388608);
  float* cosT = (float*)(ws + 16777216 + 25165824 + 8388608 + 50331648);
  float* sinT = cosT + 2048 * 32;
  u16* AttO = Xbf;    // Xbf dead after projection GEMM
  u16* VtG  = WcatT;  // WcatT dead after projection GEMM

  dim3 tb(32, 8);
  prep_all_k<<<dim3(64, 64, 8), tb, 0, stream>>>(x, wq_sem, wk_sem, wq_geo, wk_geo,
                                                 wv, wo, WcatT, WoT, Xbf, cosT, sinT);

  // proj: BN=384 -> grid 16x32 = 512 blocks = 2 balanced rounds at 1 block/CU
  gemm4_k<6, false><<<dim3(16, 32), 256, 0, stream>>>(Xbf, WcatT, P, 4096, 6144, 2048);
  // fused vectorized RoPE (blocks 0..2047) + V-transpose (blocks 2048..10239)
  ropevt_k<<<10240, 256, 0, stream>>>(P, cosT, sinT, VtG);
  attn_k<<<dim3(256, 2), 256, 0, stream>>>(P, VtG, gate, AttO);
  // wo: BN=256 -> grid 8x32 = 256 blocks = 1 balanced round
  gemm4_k<4, true><<<dim3(8, 32), 256, 0, stream>>>(AttO, WoT, d_out, 4096, 2048, 2048);
}

// Round 15
// 250.547 us; speedup vs baseline: 1.1332x; 1.0185x over previous
//
#include <hip/hip_runtime.h>
#include <hip/hip_bf16.h>

typedef unsigned short u16;
typedef __attribute__((ext_vector_type(4))) float floatx4;
typedef __attribute__((ext_vector_type(8))) __bf16 bf16x8;

// ---------- helpers ----------
__device__ __forceinline__ u16 f2bf(float f) {
  unsigned int x = __builtin_bit_cast(unsigned int, f);
  unsigned int r = (x + 0x7fffu + ((x >> 16) & 1u)) >> 16;
  return (u16)r;
}
__device__ __forceinline__ float bf2f(u16 u) {
  unsigned int x = ((unsigned int)u) << 16;
  return __builtin_bit_cast(float, x);
}
__device__ __forceinline__ floatx4 mfma16(bf16x8 a, bf16x8 b, floatx4 c) {
  return __builtin_amdgcn_mfma_f32_16x16x32_bf16(a, b, c, 0, 0, 0);
}
__device__ __forceinline__ void gload16(const u16* g, u16* l) {
  __builtin_amdgcn_global_load_lds(
      (const __attribute__((address_space(1))) unsigned int*)g,
      (__attribute__((address_space(3))) unsigned int*)l, 16, 0, 0);
}
#define SCHEDB() __builtin_amdgcn_sched_barrier(0)
#define SBAR() __builtin_amdgcn_s_barrier()

// ---------- sizes ----------
#define BB 2
#define SS 2048
#define DM 2048
#define HH 16
#define PCOLS 4096   // qsem 1024 | ksem 1024 | qgeo 1024 | kgeo 1024  (V goes直接 to VtG)

// ---------- fused prep kernel ----------
// z 0..5: weight transposes (dst[c][r] = bf16(src[r][c]), rows = 2048)
// z 6   : x -> bf16
// z 7   : rope cos/sin tables
__global__ void prep_all_k(const float* __restrict__ x,
                           const float* w0, const float* w1, const float* w2,
                           const float* w3, const float* w4, const float* w5,
                           u16* __restrict__ WcatT, u16* __restrict__ WoT,
                           u16* __restrict__ Xbf,
                           float* __restrict__ cosT, float* __restrict__ sinT) {
  const int z = blockIdx.z;
  const int tx = threadIdx.x, ty = threadIdx.y;
  const int ftid = ty * 32 + tx;               // 0..255

  if (z == 6) {  // convert x -> bf16, 8 f32 per thread
    size_t base = ((size_t)(blockIdx.y * 64 + blockIdx.x)) * 2048 + (size_t)ftid * 8;
    float4 v0 = *(const float4*)&x[base];
    float4 v1 = *(const float4*)&x[base + 4];
    ushort4 o0, o1;
    o0.x = f2bf(v0.x); o0.y = f2bf(v0.y); o0.z = f2bf(v0.z); o0.w = f2bf(v0.w);
    o1.x = f2bf(v1.x); o1.y = f2bf(v1.y); o1.z = f2bf(v1.z); o1.w = f2bf(v1.w);
    *(ushort4*)&Xbf[base] = o0;
    *(ushort4*)&Xbf[base + 4] = o1;
    return;
  }
  if (z == 7) {  // rope tables
    int lb = blockIdx.y * 64 + blockIdx.x;
    if (lb >= 256) return;
    int idx = lb * 256 + ftid;                 // 0..65535 = 2048*32
    int s = idx >> 5, d = idx & 31;
    double inv = pow(10000.0, -(double)d / 32.0);
    double ang = (double)s * inv;
    cosT[idx] = (float)cos(ang);
    sinT[idx] = (float)sin(ang);
    return;
  }

  // z 0..5: weight transpose
  __shared__ float tile[32][33];
  const float* src; u16* dst; int cols;
  if (z == 0)      { src = w0; dst = WcatT;                        cols = 1024; }
  else if (z == 1) { src = w1; dst = WcatT + (size_t)1024 * 2048;  cols = 1024; }
  else if (z == 2) { src = w2; dst = WcatT + (size_t)2048 * 2048;  cols = 1024; }
  else if (z == 3) { src = w3; dst = WcatT + (size_t)3072 * 2048;  cols = 1024; }
  else if (z == 4) { src = w4; dst = WcatT + (size_t)4096 * 2048;  cols = 2048; }
  else             { src = w5; dst = WoT;                          cols = 2048; }
  int c0 = blockIdx.x * 32;
  if (c0 >= cols) return;
  int r0 = blockIdx.y * 32;
#pragma unroll
  for (int i = 0; i < 4; ++i)
    tile[ty + i * 8][tx] = src[(size_t)(r0 + ty + i * 8) * cols + c0 + tx];
  __syncthreads();
#pragma unroll
  for (int i = 0; i < 4; ++i)
    dst[(size_t)(c0 + ty + i * 8) * 2048 + r0 + tx] = f2bf(tile[tx][ty + i * 8]);
}

// ---------- vectorized in-place RoPE on P qgeo (cols 2048..3071) / kgeo (3072..4095) ----------
__global__ void rope_k(u16* __restrict__ P, const float* __restrict__ cosT,
                       const float* __restrict__ sinT) {
  int idx = blockIdx.x * 256 + threadIdx.x;    // rows(4096)*2*16*4 = 524288
  int d0 = (idx & 3) * 8;                      // 0,8,16,24
  int h = (idx >> 2) & 15, reg = (idx >> 6) & 1, row = idx >> 7;
  int s = row & (SS - 1);
  size_t base = (size_t)row * PCOLS + (reg ? 3072 : 2048) + h * 64 + d0;
  uint4 x1 = *(const uint4*)&P[base];
  uint4 x2 = *(const uint4*)&P[base + 32];
  const u16* x1v = (const u16*)&x1;
  const u16* x2v = (const u16*)&x2;
  float cv[8], sv[8];
  *(float4*)&cv[0] = *(const float4*)&cosT[s * 32 + d0];
  *(float4*)&cv[4] = *(const float4*)&cosT[s * 32 + d0 + 4];
  *(float4*)&sv[0] = *(const float4*)&sinT[s * 32 + d0];
  *(float4*)&sv[4] = *(const float4*)&sinT[s * 32 + d0 + 4];
  u16 o1v[8], o2v[8];
#pragma unroll
  for (int j = 0; j < 8; ++j) {
    float a1 = bf2f(x1v[j]), a2 = bf2f(x2v[j]);
    o1v[j] = f2bf(a1 * cv[j] - a2 * sv[j]);
    o2v[j] = f2bf(a1 * sv[j] + a2 * cv[j]);
  }
  *(uint4*)&P[base] = *(const uint4*)o1v;
  *(uint4*)&P[base + 32] = *(const uint4*)o2v;
}

// ---------- 8-phase GEMM, 4 waves, big per-wave tile ----------
// VSPLIT (proj): output cols <4096 -> P[row][col] (stride 4096, bf16);
//                cols >=4096 (V)  -> VtG[(b*2048 + col-4096)][s] as ushort4 (transposed, free)
template <int NFB, bool OUTF32, bool VSPLIT>
__global__ __launch_bounds__(256, 1)
void gemm4_k(const u16* __restrict__ A, const u16* __restrict__ Bt,
             void* __restrict__ Cout, u16* __restrict__ VtGo, int M, int N, int K) {
  constexpr int BH = NFB / 2;              // bfv frags per phase
  __shared__ alignas(16) u16 lds[16384 + NFB * 8192];
  const int tid = threadIdx.x;
  const int wid = tid >> 6, lane = tid & 63;
  const int lr = lane & 15, lg = lane >> 4;
  const int m0 = blockIdx.y * 128, n0 = blockIdx.x * (NFB * 64);
  const int NT = K >> 6;                   // K-tiles of 64
  const int NSLAB = NT * 4;

  const int aoff = lr * 32 + ((lg ^ ((lr >> 1) & 3)) * 8);

  const int srow = wid * 16 + (lane >> 2);
  const int sgl = (((lane & 3) ^ ((lane >> 3) & 3)) * 8);
  const u16* Asrc = A + (size_t)(m0 + srow) * K + sgl;
  const u16* Bsrc = Bt + (size_t)(n0 + srow) * K + sgl;

  floatx4 acc[8][NFB];
#pragma unroll
  for (int m = 0; m < 8; ++m)
#pragma unroll
    for (int n = 0; n < NFB; ++n) acc[m][n] = (floatx4){0.f, 0.f, 0.f, 0.f};

  auto stgA = [&](int tile, int kh) {
    u16* d = lds + ((tile & 1) * 2 + kh) * 4096 + wid * 512;
    const u16* s = Asrc + tile * 64 + kh * 32;
#pragma unroll
    for (int c = 0; c < 2; ++c) gload16(s + (size_t)(c * 64) * K, d + c * 2048);
  };
  auto stgB = [&](int tile, int kh) {
    u16* d = lds + 16384 + ((tile & 1) * 2 + kh) * (NFB * 2048) + wid * 512;
    const u16* s = Bsrc + tile * 64 + kh * 32;
#pragma unroll
    for (int c = 0; c < NFB; ++c) gload16(s + (size_t)(c * 64) * K, d + c * 2048);
  };
  auto stage_slab = [&](int s) {
    if (s >= NSLAB) return;
    int tile = s >> 2, kind = s & 3;
    if (kind == 0) stgA(tile, 0);
    else if (kind == 1) stgB(tile, 0);
    else if (kind == 2) stgA(tile, 1);
    else stgB(tile, 1);
  };

  for (int s = 0; s < 7; ++s) stage_slab(s);
  if constexpr (NFB == 6) asm volatile("s_waitcnt vmcnt(10)" ::: "memory");
  else                    asm volatile("s_waitcnt vmcnt(8)" ::: "memory");
  SCHEDB(); SBAR(); SCHEDB();

  bf16x8 af[8], bfv[BH];

#pragma unroll 1
  for (int it = 0; it < (NT >> 1); ++it) {
    const int t = it * 2;
    const int sb = t * 4 + 6;
    const bool more = (t + 2 < NT);

#define PH(BUF, KK, NH, SL, DOVM)                                               \
    {                                                                           \
      const u16* Ab = lds + ((BUF) * 2 + (KK)) * 4096;                          \
      const u16* Bb = lds + 16384 + ((BUF) * 2 + (KK)) * (NFB * 2048);          \
      if ((NH) == 0) {                                                          \
        _Pragma("unroll") for (int m = 0; m < 8; ++m)                           \
          af[m] = *(const bf16x8*)&Ab[(m * 16) * 32 + aoff];                    \
      }                                                                         \
      _Pragma("unroll") for (int j = 0; j < BH; ++j)                            \
        bfv[j] = *(const bf16x8*)&Bb[(wid * NFB * 16 + ((NH) * BH + j) * 16) * 32 + aoff]; \
      stage_slab(sb + (SL));                                                    \
      SCHEDB(); SBAR(); SCHEDB();                                               \
      __builtin_amdgcn_s_setprio(1);                                            \
      _Pragma("unroll") for (int m = 0; m < 8; ++m)                             \
        _Pragma("unroll") for (int j = 0; j < BH; ++j)                          \
          acc[m][(NH) * BH + j] = mfma16(af[m], bfv[j], acc[m][(NH) * BH + j]); \
      __builtin_amdgcn_s_setprio(0);                                            \
      if (DOVM) {                                                               \
        if (more) {                                                             \
          if constexpr (NFB == 6) asm volatile("s_waitcnt vmcnt(10)" ::: "memory"); \
          else                    asm volatile("s_waitcnt vmcnt(8)" ::: "memory");  \
        } else {                                                                \
          asm volatile("s_waitcnt vmcnt(0)" ::: "memory");                      \
        }                                                                       \
      }                                                                         \
      SCHEDB(); SBAR(); SCHEDB();                                               \
    }

    PH(0, 0, 0, 1, 0)
    PH(0, 0, 1, 2, 0)
    PH(0, 1, 0, 3, 0)
    PH(0, 1, 1, 4, 1)
    PH(1, 0, 0, 5, 0)
    PH(1, 0, 1, 6, 0)
    PH(1, 1, 0, 7, 0)
    PH(1, 1, 1, 8, 1)
#undef PH
  }

  // epilogue
#pragma unroll
  for (int m = 0; m < 8; ++m) {
    int row0 = m0 + m * 16 + lg * 4;
#pragma unroll
    for (int n = 0; n < NFB; ++n) {
      int col = n0 + wid * NFB * 16 + n * 16 + lr;
      if constexpr (VSPLIT) {
        if (col < 4096) {
#pragma unroll
          for (int r = 0; r < 4; ++r)
            ((u16*)Cout)[(size_t)(row0 + r) * 4096 + col] = f2bf(acc[m][n][r]);
        } else {
          ushort4 o;
          o.x = f2bf(acc[m][n][0]); o.y = f2bf(acc[m][n][1]);
          o.z = f2bf(acc[m][n][2]); o.w = f2bf(acc[m][n][3]);
          int bb = row0 >> 11, s = row0 & (SS - 1);
          *(ushort4*)&VtGo[((size_t)bb * 2048 + (col - 4096)) * SS + s] = o;
        }
      } else {
#pragma unroll
        for (int r = 0; r < 4; ++r) {
          size_t off = (size_t)(row0 + r) * N + col;
          if (OUTF32) ((float*)Cout)[off] = acc[m][n][r];
          else        ((u16*)Cout)[off] = f2bf(acc[m][n][r]);
        }
      }
    }
  }
}

// ---------- flash attention: swapped QK^T, per-lane softmax, pair-balanced, defer-max ----------
__device__ __forceinline__ bf16x8 load_scaled(const u16* p, float s) {
  uint4 raw = *(const uint4*)p;
  const u16* ru = (const u16*)&raw;
  bf16x8 out;
#pragma unroll
  for (int j = 0; j < 8; ++j) out[j] = (__bf16)(bf2f(ru[j]) * s);
  return out;
}

__global__ __launch_bounds__(256, 3)
void attn_k(const u16* __restrict__ P, const u16* __restrict__ VtG,
            const float* __restrict__ gate, u16* __restrict__ AttO) {
  // grid: x = 256 (pair 0..15 x 16 heads), y = B. Block does q-tiles pairi and 31-pairi
  // (64 rows each): (pairi+1) + (32-pairi) = 33 kv-iterations per block — perfect balance.
  const int pairi = blockIdx.x >> 4;
  const int h = blockIdx.x & 15;
  const int b = blockIdx.y;
  const int tid = threadIdx.x, wid = tid >> 6, lane = tid & 63;
  const int lr = lane & 15, lg = lane >> 4;
  const size_t rowb = (size_t)b * SS;

  const float g = 1.f / (1.f + __expf(-gate[h]));
  const float ssc = g * 0.125f;          // g / sqrt(DS)
  const float gsc = (1.f - g) * 0.125f;  // (1-g) / sqrt(DG)

  // all tiles [rows][64] linear, granule-swizzled: byte ^= (row&7)<<4
  __shared__ alignas(16) u16 Ks[64 * 64];
  __shared__ alignas(16) u16 Kg[64 * 64];
  __shared__ alignas(16) u16 Vt[128 * 64];
  __shared__ alignas(16) u16 Pw[4][16 * 64];

  const int strow = tid >> 3;                 // 0..31
  const int stg = ((tid & 7) ^ (strow & 7)) * 8;
  const int swz = lr & 7;                     // read-side swizzle (row&7 == lr&7)

  for (int half = 0; half < 2; ++half) {
    const int qb = half ? (31 - pairi) : pairi;
    const int q0 = qb * 64;

    // Q fragments (B-operand: lane holds Q[q = q0+wid*16+lr][k = kk*32+lg*8..+7])
    const u16* qbase = P + (rowb + q0 + wid * 16 + lr) * PCOLS + h * 64;
    bf16x8 qs[2], qg[2];
#pragma unroll
    for (int kk = 0; kk < 2; ++kk) {
      qs[kk] = load_scaled(qbase + kk * 32 + lg * 8, ssc);
      qg[kk] = load_scaled(qbase + 2048 + kk * 32 + lg * 8, gsc);
    }

    float m_r = -1e30f, l_r = 0.f;
    floatx4 o[8];
#pragma unroll
    for (int n = 0; n < 8; ++n) o[n] = (floatx4){0.f, 0.f, 0.f, 0.f};

    const int nkv = q0 + 64;
    for (int kv0 = 0; kv0 < nkv; kv0 += 64) {
      __syncthreads();
      {  // stage K_sem/K_geo rows 0..63 via global_load_lds (linear dest, pre-swizzled src)
        const u16* ks = P + (rowb + kv0 + strow) * PCOLS + 1024 + h * 64 + stg;
        const u16* gs = P + (rowb + kv0 + strow) * PCOLS + 3072 + h * 64 + stg;
        gload16(ks, Ks + wid * 512);
        gload16(gs, Kg + wid * 512);
        gload16(ks + (size_t)32 * PCOLS, Ks + 2048 + wid * 512);
        gload16(gs + (size_t)32 * PCOLS, Kg + 2048 + wid * 512);
      }
      {  // stage V^T rows (dv) 0..127
        const u16* vs = VtG + ((size_t)b * 2048 + h * 128 + strow) * SS + kv0 + stg;
#pragma unroll
        for (int c = 0; c < 4; ++c)
          gload16(vs + (size_t)(c * 32) * SS, Vt + c * 2048 + wid * 512);
      }
      __syncthreads();   // compiler drains vmcnt before barrier

      // swapped QK^T: lane holds score(q=q0+wid*16+lr, k=kv0+s*16+lg*4+r)
      floatx4 sc[4];
#pragma unroll
      for (int s = 0; s < 4; ++s) sc[s] = (floatx4){0.f, 0.f, 0.f, 0.f};
      __builtin_amdgcn_s_setprio(1);
#pragma unroll
      for (int kk = 0; kk < 2; ++kk) {
#pragma unroll
        for (int s = 0; s < 4; ++s) {
          bf16x8 kf = *(const bf16x8*)&Ks[(s * 16 + lr) * 64 + ((kk * 4 + lg) ^ swz) * 8];
          bf16x8 gf = *(const bf16x8*)&Kg[(s * 16 + lr) * 64 + ((kk * 4 + lg) ^ swz) * 8];
          sc[s] = mfma16(kf, qs[kk], sc[s]);
          sc[s] = mfma16(gf, qg[kk], sc[s]);
        }
      }
      __builtin_amdgcn_s_setprio(0);

      // per-lane softmax over this lane's 16 values (its q-row = lr)
      const int qrow = q0 + wid * 16 + lr;
      const bool needmask = (kv0 + 63 > q0 + wid * 16);
      float vv[4][4];
      float vmax = -1e30f;
#pragma unroll
      for (int s = 0; s < 4; ++s)
#pragma unroll
        for (int r = 0; r < 4; ++r) {
          float val = sc[s][r];
          if (needmask) val = (kv0 + s * 16 + lg * 4 + r <= qrow) ? val : -1e30f;
          vv[s][r] = val;
          vmax = fmaxf(vmax, val);
        }
      vmax = fmaxf(vmax, __shfl_xor(vmax, 16));
      vmax = fmaxf(vmax, __shfl_xor(vmax, 32));

      // T13 defer-max: if row max grew by <= 8 for ALL rows of this wave, keep m_r
      // (P bounded by e^8 — same relative bf16 precision) and skip the O-rescale.
      const bool defer = __all(vmax - m_r <= 8.0f);
      const float mnew = defer ? m_r : fmaxf(m_r, vmax);
      float psum = 0.f;
#pragma unroll
      for (int s = 0; s < 4; ++s)
#pragma unroll
        for (int r = 0; r < 4; ++r) {
          vv[s][r] = __expf(vv[s][r] - mnew);
          psum += vv[s][r];
        }
      psum += __shfl_xor(psum, 16);
      psum += __shfl_xor(psum, 32);

      // pack P to bf16 pairs, write swizzled: value k=s*16+lg*4+2t(,+1) at row lr
#pragma unroll
      for (int s = 0; s < 4; ++s)
#pragma unroll
        for (int t = 0; t < 2; ++t) {
          unsigned int w;
          asm("v_cvt_pk_bf16_f32 %0, %1, %2" : "=v"(w) : "v"(vv[s][2 * t]), "v"(vv[s][2 * t + 1]));
          int u16off = lr * 64 + ((s * 2 + (lg >> 1)) ^ swz) * 8 + (lg & 1) * 4 + t * 2;
          *(unsigned int*)&Pw[wid][u16off] = w;
        }

      // rescale (skipped when deferred) — VALU here overlaps the Pw ds_write latency
      if (!defer) {
        float corr = __expf(m_r - mnew);
        l_r *= corr;
        m_r = mnew;
        float crr[4];
#pragma unroll
        for (int r = 0; r < 4; ++r) crr[r] = __shfl(corr, lg * 4 + r);
#pragma unroll
        for (int n = 0; n < 8; ++n)
#pragma unroll
          for (int r = 0; r < 4; ++r) o[n][r] *= crr[r];
      }
      l_r += psum;

      asm volatile("s_waitcnt lgkmcnt(0)" ::: "memory");
      SCHEDB();
      // PV: A = P[q=lr][k-chunk], B = Vt[dv=n*16+lr][k-chunk]
      bf16x8 pa0 = *(const bf16x8*)&Pw[wid][lr * 64 + (lg ^ swz) * 8];
      bf16x8 pa1 = *(const bf16x8*)&Pw[wid][lr * 64 + ((4 + lg) ^ swz) * 8];
      __builtin_amdgcn_s_setprio(1);
#pragma unroll
      for (int n = 0; n < 8; ++n) {
        bf16x8 vb0 = *(const bf16x8*)&Vt[(n * 16 + lr) * 64 + (lg ^ swz) * 8];
        bf16x8 vb1 = *(const bf16x8*)&Vt[(n * 16 + lr) * 64 + ((4 + lg) ^ swz) * 8];
        o[n] = mfma16(pa0, vb0, o[n]);
        o[n] = mfma16(pa1, vb1, o[n]);
      }
      __builtin_amdgcn_s_setprio(0);
    }

    float linv = 1.f / l_r;
    float lnv[4];
#pragma unroll
    for (int r = 0; r < 4; ++r) lnv[r] = __shfl(linv, lg * 4 + r);
#pragma unroll
    for (int n = 0; n < 8; ++n)
#pragma unroll
      for (int r = 0; r < 4; ++r) {
        float val = o[n][r] * lnv[r];
        AttO[(rowb + q0 + wid * 16 + lg * 4 + r) * (size_t)(HH * 128) + h * 128 + n * 16 + lr] =
            f2bf(val);
      }
  }
}

// ---------- launch ----------
extern "C" void kernel_launch(void* const* d_in, const int* in_sizes, int n_in,
                              void* d_out, int out_size, void* d_ws, size_t ws_size,
                              hipStream_t stream) {
  const float* x       = (const float*)d_in[0];
  const float* wq_sem  = (const float*)d_in[1];
  const float* wk_sem  = (const float*)d_in[2];
  const float* wq_geo  = (const float*)d_in[3];
  const float* wk_geo  = (const float*)d_in[4];
  const float* wv      = (const float*)d_in[5];
  const float* wo      = (const float*)d_in[6];
  const float* gate    = (const float*)d_in[7];

  char* ws = (char*)d_ws;
  // layout (bytes):
  //  Xbf   @ 0           : 16,777,216   (reused later as AttO)
  //  WcatT @ 16,777,216  : 25,165,824   (proj B — read during proj, dead after)
  //  WoT   @ 41,943,040  :  8,388,608
  //  P     @ 50,331,648  : 33,554,432   (4096 x 4096 bf16: qsem|ksem|qgeo|kgeo)
  //  VtG   @ 83,886,080  : 16,777,216   (V transposed, written by proj epilogue)
  //  cosT  @ 100,663,296 : 262,144 ; sinT follows  (total 101,187,584 — same as before)
  u16* Xbf   = (u16*)(ws);
  u16* WcatT = (u16*)(ws + 16777216);
  u16* WoT   = (u16*)(ws + 41943040);
  u16* P     = (u16*)(ws + 50331648);
  u16* VtG   = (u16*)(ws + 83886080);
  float* cosT = (float*)(ws + 100663296);
  float* sinT = cosT + 2048 * 32;
  u16* AttO = Xbf;    // Xbf dead after projection GEMM

  dim3 tb(32, 8);
  prep_all_k<<<dim3(64, 64, 8), tb, 0, stream>>>(x, wq_sem, wk_sem, wq_geo, wk_geo,
                                                 wv, wo, WcatT, WoT, Xbf, cosT, sinT);

  // proj: BN=384 -> grid 16x32 = 512 blocks; Q/K cols -> P, V cols -> VtG (transposed)
  gemm4_k<6, false, true><<<dim3(16, 32), 256, 0, stream>>>(Xbf, WcatT, P, VtG,
                                                            4096, 6144, 2048);
  // vectorized in-place RoPE on P qgeo/kgeo
  rope_k<<<2048, 256, 0, stream>>>(P, cosT, sinT);
  attn_k<<<dim3(256, 2), 256, 0, stream>>>(P, VtG, gate, AttO);
  // wo: BN=256 -> grid 8x32 = 256 blocks = 1 balanced round
  gemm4_k<4, true, false><<<dim3(8, 32), 256, 0, stream>>>(AttO, WoT, d_out, nullptr,
                                                           4096, 2048, 2048);
}

// Round 16
// 250.270 us; speedup vs baseline: 1.1344x; 1.0011x over previous
//
#include <hip/hip_runtime.h>
#include <hip/hip_bf16.h>

typedef unsigned short u16;
typedef __attribute__((ext_vector_type(4))) float floatx4;
typedef __attribute__((ext_vector_type(8))) __bf16 bf16x8;

// ---------- helpers ----------
__device__ __forceinline__ u16 f2bf(float f) {
  unsigned int x = __builtin_bit_cast(unsigned int, f);
  unsigned int r = (x + 0x7fffu + ((x >> 16) & 1u)) >> 16;
  return (u16)r;
}
__device__ __forceinline__ float bf2f(u16 u) {
  unsigned int x = ((unsigned int)u) << 16;
  return __builtin_bit_cast(float, x);
}
__device__ __forceinline__ floatx4 mfma16(bf16x8 a, bf16x8 b, floatx4 c) {
  return __builtin_amdgcn_mfma_f32_16x16x32_bf16(a, b, c, 0, 0, 0);
}
__device__ __forceinline__ void gload16(const u16* g, u16* l) {
  __builtin_amdgcn_global_load_lds(
      (const __attribute__((address_space(1))) unsigned int*)g,
      (__attribute__((address_space(3))) unsigned int*)l, 16, 0, 0);
}
#define SCHEDB() __builtin_amdgcn_sched_barrier(0)
#define SBAR() __builtin_amdgcn_s_barrier()

// ---------- sizes ----------
#define BB 2
#define SS 2048
#define DM 2048
#define HH 16
#define PCOLS 4096   // qsem 1024 | ksem 1024 | qgeo 1024 | kgeo 1024  (V direct to VtG)

// ---------- fused prep kernel ----------
__global__ void prep_all_k(const float* __restrict__ x,
                           const float* w0, const float* w1, const float* w2,
                           const float* w3, const float* w4, const float* w5,
                           u16* __restrict__ WcatT, u16* __restrict__ WoT,
                           u16* __restrict__ Xbf,
                           float* __restrict__ cosT, float* __restrict__ sinT) {
  const int z = blockIdx.z;
  const int tx = threadIdx.x, ty = threadIdx.y;
  const int ftid = ty * 32 + tx;               // 0..255

  if (z == 6) {  // convert x -> bf16, 8 f32 per thread
    size_t base = ((size_t)(blockIdx.y * 64 + blockIdx.x)) * 2048 + (size_t)ftid * 8;
    float4 v0 = *(const float4*)&x[base];
    float4 v1 = *(const float4*)&x[base + 4];
    ushort4 o0, o1;
    o0.x = f2bf(v0.x); o0.y = f2bf(v0.y); o0.z = f2bf(v0.z); o0.w = f2bf(v0.w);
    o1.x = f2bf(v1.x); o1.y = f2bf(v1.y); o1.z = f2bf(v1.z); o1.w = f2bf(v1.w);
    *(ushort4*)&Xbf[base] = o0;
    *(ushort4*)&Xbf[base + 4] = o1;
    return;
  }
  if (z == 7) {  // rope tables
    int lb = blockIdx.y * 64 + blockIdx.x;
    if (lb >= 256) return;
    int idx = lb * 256 + ftid;                 // 0..65535 = 2048*32
    int s = idx >> 5, d = idx & 31;
    double inv = pow(10000.0, -(double)d / 32.0);
    double ang = (double)s * inv;
    cosT[idx] = (float)cos(ang);
    sinT[idx] = (float)sin(ang);
    return;
  }

  // z 0..5: weight transpose
  __shared__ float tile[32][33];
  const float* src; u16* dst; int cols;
  if (z == 0)      { src = w0; dst = WcatT;                        cols = 1024; }
  else if (z == 1) { src = w1; dst = WcatT + (size_t)1024 * 2048;  cols = 1024; }
  else if (z == 2) { src = w2; dst = WcatT + (size_t)2048 * 2048;  cols = 1024; }
  else if (z == 3) { src = w3; dst = WcatT + (size_t)3072 * 2048;  cols = 1024; }
  else if (z == 4) { src = w4; dst = WcatT + (size_t)4096 * 2048;  cols = 2048; }
  else             { src = w5; dst = WoT;                          cols = 2048; }
  int c0 = blockIdx.x * 32;
  if (c0 >= cols) return;
  int r0 = blockIdx.y * 32;
#pragma unroll
  for (int i = 0; i < 4; ++i)
    tile[ty + i * 8][tx] = src[(size_t)(r0 + ty + i * 8) * cols + c0 + tx];
  __syncthreads();
#pragma unroll
  for (int i = 0; i < 4; ++i)
    dst[(size_t)(c0 + ty + i * 8) * 2048 + r0 + tx] = f2bf(tile[tx][ty + i * 8]);
}

// ---------- vectorized in-place RoPE on P kgeo only (cols 3072..4095) ----------
// (Q-side RoPE is folded into attn_k's register Q-load.)
__global__ void rope_k(u16* __restrict__ P, const float* __restrict__ cosT,
                       const float* __restrict__ sinT) {
  int idx = blockIdx.x * 256 + threadIdx.x;    // rows(4096)*16*4 = 262144
  int d0 = (idx & 3) * 8;                      // 0,8,16,24
  int h = (idx >> 2) & 15, row = idx >> 6;
  int s = row & (SS - 1);
  size_t base = (size_t)row * PCOLS + 3072 + h * 64 + d0;
  uint4 x1 = *(const uint4*)&P[base];
  uint4 x2 = *(const uint4*)&P[base + 32];
  const u16* x1v = (const u16*)&x1;
  const u16* x2v = (const u16*)&x2;
  float cv[8], sv[8];
  *(float4*)&cv[0] = *(const float4*)&cosT[s * 32 + d0];
  *(float4*)&cv[4] = *(const float4*)&cosT[s * 32 + d0 + 4];
  *(float4*)&sv[0] = *(const float4*)&sinT[s * 32 + d0];
  *(float4*)&sv[4] = *(const float4*)&sinT[s * 32 + d0 + 4];
  u16 o1v[8], o2v[8];
#pragma unroll
  for (int j = 0; j < 8; ++j) {
    float a1 = bf2f(x1v[j]), a2 = bf2f(x2v[j]);
    o1v[j] = f2bf(a1 * cv[j] - a2 * sv[j]);
    o2v[j] = f2bf(a1 * sv[j] + a2 * cv[j]);
  }
  *(uint4*)&P[base] = *(const uint4*)o1v;
  *(uint4*)&P[base + 32] = *(const uint4*)o2v;
}

// ---------- 8-phase GEMM, 4 waves, big per-wave tile ----------
// VSPLIT (proj): output cols <4096 -> P[row][col] (stride 4096, bf16);
//                cols >=4096 (V)  -> VtG[(b*2048 + col-4096)][s] as ushort4 (transposed, free)
template <int NFB, bool OUTF32, bool VSPLIT>
__global__ __launch_bounds__(256, 1)
void gemm4_k(const u16* __restrict__ A, const u16* __restrict__ Bt,
             void* __restrict__ Cout, u16* __restrict__ VtGo, int M, int N, int K) {
  constexpr int BH = NFB / 2;              // bfv frags per phase
  __shared__ alignas(16) u16 lds[16384 + NFB * 8192];
  const int tid = threadIdx.x;
  const int wid = tid >> 6, lane = tid & 63;
  const int lr = lane & 15, lg = lane >> 4;
  const int m0 = blockIdx.y * 128, n0 = blockIdx.x * (NFB * 64);
  const int NT = K >> 6;                   // K-tiles of 64
  const int NSLAB = NT * 4;

  const int aoff = lr * 32 + ((lg ^ ((lr >> 1) & 3)) * 8);

  const int srow = wid * 16 + (lane >> 2);
  const int sgl = (((lane & 3) ^ ((lane >> 3) & 3)) * 8);
  const u16* Asrc = A + (size_t)(m0 + srow) * K + sgl;
  const u16* Bsrc = Bt + (size_t)(n0 + srow) * K + sgl;

  floatx4 acc[8][NFB];
#pragma unroll
  for (int m = 0; m < 8; ++m)
#pragma unroll
    for (int n = 0; n < NFB; ++n) acc[m][n] = (floatx4){0.f, 0.f, 0.f, 0.f};

  auto stgA = [&](int tile, int kh) {
    u16* d = lds + ((tile & 1) * 2 + kh) * 4096 + wid * 512;
    const u16* s = Asrc + tile * 64 + kh * 32;
#pragma unroll
    for (int c = 0; c < 2; ++c) gload16(s + (size_t)(c * 64) * K, d + c * 2048);
  };
  auto stgB = [&](int tile, int kh) {
    u16* d = lds + 16384 + ((tile & 1) * 2 + kh) * (NFB * 2048) + wid * 512;
    const u16* s = Bsrc + tile * 64 + kh * 32;
#pragma unroll
    for (int c = 0; c < NFB; ++c) gload16(s + (size_t)(c * 64) * K, d + c * 2048);
  };
  auto stage_slab = [&](int s) {
    if (s >= NSLAB) return;
    int tile = s >> 2, kind = s & 3;
    if (kind == 0) stgA(tile, 0);
    else if (kind == 1) stgB(tile, 0);
    else if (kind == 2) stgA(tile, 1);
    else stgB(tile, 1);
  };

  for (int s = 0; s < 7; ++s) stage_slab(s);
  if constexpr (NFB == 6) asm volatile("s_waitcnt vmcnt(10)" ::: "memory");
  else                    asm volatile("s_waitcnt vmcnt(8)" ::: "memory");
  SCHEDB(); SBAR(); SCHEDB();

  bf16x8 af[8], bfv[BH];

#pragma unroll 1
  for (int it = 0; it < (NT >> 1); ++it) {
    const int t = it * 2;
    const int sb = t * 4 + 6;
    const bool more = (t + 2 < NT);

#define PH(BUF, KK, NH, SL, DOVM)                                               \
    {                                                                           \
      const u16* Ab = lds + ((BUF) * 2 + (KK)) * 4096;                          \
      const u16* Bb = lds + 16384 + ((BUF) * 2 + (KK)) * (NFB * 2048);          \
      if ((NH) == 0) {                                                          \
        _Pragma("unroll") for (int m = 0; m < 8; ++m)                           \
          af[m] = *(const bf16x8*)&Ab[(m * 16) * 32 + aoff];                    \
      }                                                                         \
      _Pragma("unroll") for (int j = 0; j < BH; ++j)                            \
        bfv[j] = *(const bf16x8*)&Bb[(wid * NFB * 16 + ((NH) * BH + j) * 16) * 32 + aoff]; \
      stage_slab(sb + (SL));                                                    \
      SCHEDB(); SBAR(); SCHEDB();                                               \
      __builtin_amdgcn_s_setprio(1);                                            \
      _Pragma("unroll") for (int m = 0; m < 8; ++m)                             \
        _Pragma("unroll") for (int j = 0; j < BH; ++j)                          \
          acc[m][(NH) * BH + j] = mfma16(af[m], bfv[j], acc[m][(NH) * BH + j]); \
      __builtin_amdgcn_s_setprio(0);                                            \
      if (DOVM) {                                                               \
        if (more) {                                                             \
          if constexpr (NFB == 6) asm volatile("s_waitcnt vmcnt(10)" ::: "memory"); \
          else                    asm volatile("s_waitcnt vmcnt(8)" ::: "memory");  \
        } else {                                                                \
          asm volatile("s_waitcnt vmcnt(0)" ::: "memory");                      \
        }                                                                       \
      }                                                                         \
      SCHEDB(); SBAR(); SCHEDB();                                               \
    }

    PH(0, 0, 0, 1, 0)
    PH(0, 0, 1, 2, 0)
    PH(0, 1, 0, 3, 0)
    PH(0, 1, 1, 4, 1)
    PH(1, 0, 0, 5, 0)
    PH(1, 0, 1, 6, 0)
    PH(1, 1, 0, 7, 0)
    PH(1, 1, 1, 8, 1)
#undef PH
  }

  // epilogue
#pragma unroll
  for (int m = 0; m < 8; ++m) {
    int row0 = m0 + m * 16 + lg * 4;
#pragma unroll
    for (int n = 0; n < NFB; ++n) {
      int col = n0 + wid * NFB * 16 + n * 16 + lr;
      if constexpr (VSPLIT) {
        if (col < 4096) {
#pragma unroll
          for (int r = 0; r < 4; ++r)
            ((u16*)Cout)[(size_t)(row0 + r) * 4096 + col] = f2bf(acc[m][n][r]);
        } else {
          ushort4 o;
          o.x = f2bf(acc[m][n][0]); o.y = f2bf(acc[m][n][1]);
          o.z = f2bf(acc[m][n][2]); o.w = f2bf(acc[m][n][3]);
          int bb = row0 >> 11, s = row0 & (SS - 1);
          *(ushort4*)&VtGo[((size_t)bb * 2048 + (col - 4096)) * SS + s] = o;
        }
      } else {
#pragma unroll
        for (int r = 0; r < 4; ++r) {
          size_t off = (size_t)(row0 + r) * N + col;
          if (OUTF32) ((float*)Cout)[off] = acc[m][n][r];
          else        ((u16*)Cout)[off] = f2bf(acc[m][n][r]);
        }
      }
    }
  }
}

// ---------- flash attention: swapped QK^T, per-lane softmax, pair-balanced, defer-max,
// ---------- Q-side RoPE folded into the register Q-load ----------
__device__ __forceinline__ bf16x8 load_scaled(const u16* p, float s) {
  uint4 raw = *(const uint4*)p;
  const u16* ru = (const u16*)&raw;
  bf16x8 out;
#pragma unroll
  for (int j = 0; j < 8; ++j) out[j] = (__bf16)(bf2f(ru[j]) * s);
  return out;
}

__global__ __launch_bounds__(256, 3)
void attn_k(const u16* __restrict__ P, const u16* __restrict__ VtG,
            const float* __restrict__ gate, const float* __restrict__ cosT,
            const float* __restrict__ sinT, u16* __restrict__ AttO) {
  // grid: x = 256 (pair 0..15 x 16 heads), y = B. Block does q-tiles pairi and 31-pairi
  // (64 rows each): (pairi+1) + (32-pairi) = 33 kv-iterations per block — perfect balance.
  const int pairi = blockIdx.x >> 4;
  const int h = blockIdx.x & 15;
  const int b = blockIdx.y;
  const int tid = threadIdx.x, wid = tid >> 6, lane = tid & 63;
  const int lr = lane & 15, lg = lane >> 4;
  const size_t rowb = (size_t)b * SS;

  const float g = 1.f / (1.f + __expf(-gate[h]));
  const float ssc = g * 0.125f;          // g / sqrt(DS)
  const float gsc = (1.f - g) * 0.125f;  // (1-g) / sqrt(DG)

  // all tiles [rows][64] linear, granule-swizzled: byte ^= (row&7)<<4
  __shared__ alignas(16) u16 Ks[64 * 64];
  __shared__ alignas(16) u16 Kg[64 * 64];
  __shared__ alignas(16) u16 Vt[128 * 64];
  __shared__ alignas(16) u16 Pw[4][16 * 64];

  const int strow = tid >> 3;                 // 0..31
  const int stg = ((tid & 7) ^ (strow & 7)) * 8;
  const int swz = lr & 7;                     // read-side swizzle (row&7 == lr&7)

  for (int half = 0; half < 2; ++half) {
    const int qb = half ? (31 - pairi) : pairi;
    const int q0 = qb * 64;
    const int qrow = q0 + wid * 16 + lr;      // sequence position of this lane's Q row

    // Q fragments (B-operand: lane holds Q[qrow][k = kk*32+lg*8..+7])
    const u16* qbase = P + (rowb + qrow) * PCOLS + h * 64;
    bf16x8 qs[2], qg[2];
#pragma unroll
    for (int kk = 0; kk < 2; ++kk)
      qs[kk] = load_scaled(qbase + kk * 32 + lg * 8, ssc);
    {  // qgeo: raw load + in-register RoPE (pair (d, d+32) = (qg0[j], qg1[j])) + scale
      uint4 r0 = *(const uint4*)(qbase + 2048 + lg * 8);
      uint4 r1 = *(const uint4*)(qbase + 2048 + 32 + lg * 8);
      const u16* x1v = (const u16*)&r0;
      const u16* x2v = (const u16*)&r1;
      float cv[8], sv[8];
      *(float4*)&cv[0] = *(const float4*)&cosT[qrow * 32 + lg * 8];
      *(float4*)&cv[4] = *(const float4*)&cosT[qrow * 32 + lg * 8 + 4];
      *(float4*)&sv[0] = *(const float4*)&sinT[qrow * 32 + lg * 8];
      *(float4*)&sv[4] = *(const float4*)&sinT[qrow * 32 + lg * 8 + 4];
#pragma unroll
      for (int j = 0; j < 8; ++j) {
        float a1 = bf2f(x1v[j]), a2 = bf2f(x2v[j]);
        qg[0][j] = (__bf16)((a1 * cv[j] - a2 * sv[j]) * gsc);
        qg[1][j] = (__bf16)((a1 * sv[j] + a2 * cv[j]) * gsc);
      }
    }

    float m_r = -1e30f, l_r = 0.f;
    floatx4 o[8];
#pragma unroll
    for (int n = 0; n < 8; ++n) o[n] = (floatx4){0.f, 0.f, 0.f, 0.f};

    const int nkv = q0 + 64;
    for (int kv0 = 0; kv0 < nkv; kv0 += 64) {
      __syncthreads();
      {  // stage K_sem/K_geo rows 0..63 via global_load_lds (linear dest, pre-swizzled src)
        const u16* ks = P + (rowb + kv0 + strow) * PCOLS + 1024 + h * 64 + stg;
        const u16* gs = P + (rowb + kv0 + strow) * PCOLS + 3072 + h * 64 + stg;
        gload16(ks, Ks + wid * 512);
        gload16(gs, Kg + wid * 512);
        gload16(ks + (size_t)32 * PCOLS, Ks + 2048 + wid * 512);
        gload16(gs + (size_t)32 * PCOLS, Kg + 2048 + wid * 512);
      }
      {  // stage V^T rows (dv) 0..127
        const u16* vs = VtG + ((size_t)b * 2048 + h * 128 + strow) * SS + kv0 + stg;
#pragma unroll
        for (int c = 0; c < 4; ++c)
          gload16(vs + (size_t)(c * 32) * SS, Vt + c * 2048 + wid * 512);
      }
      __syncthreads();   // compiler drains vmcnt before barrier

      // swapped QK^T: lane holds score(q=qrow, k=kv0+s*16+lg*4+r)
      floatx4 sc[4];
#pragma unroll
      for (int s = 0; s < 4; ++s) sc[s] = (floatx4){0.f, 0.f, 0.f, 0.f};
      __builtin_amdgcn_s_setprio(1);
#pragma unroll
      for (int kk = 0; kk < 2; ++kk) {
#pragma unroll
        for (int s = 0; s < 4; ++s) {
          bf16x8 kf = *(const bf16x8*)&Ks[(s * 16 + lr) * 64 + ((kk * 4 + lg) ^ swz) * 8];
          bf16x8 gf = *(const bf16x8*)&Kg[(s * 16 + lr) * 64 + ((kk * 4 + lg) ^ swz) * 8];
          sc[s] = mfma16(kf, qs[kk], sc[s]);
          sc[s] = mfma16(gf, qg[kk], sc[s]);
        }
      }
      __builtin_amdgcn_s_setprio(0);

      // per-lane softmax over this lane's 16 values (its q-row = lr)
      const bool needmask = (kv0 + 63 > q0 + wid * 16);
      float vv[4][4];
      float vmax = -1e30f;
#pragma unroll
      for (int s = 0; s < 4; ++s)
#pragma unroll
        for (int r = 0; r < 4; ++r) {
          float val = sc[s][r];
          if (needmask) val = (kv0 + s * 16 + lg * 4 + r <= qrow) ? val : -1e30f;
          vv[s][r] = val;
          vmax = fmaxf(vmax, val);
        }
      vmax = fmaxf(vmax, __shfl_xor(vmax, 16));
      vmax = fmaxf(vmax, __shfl_xor(vmax, 32));

      // T13 defer-max: if row max grew by <= 8 for ALL rows of this wave, keep m_r
      const bool defer = __all(vmax - m_r <= 8.0f);
      const float mnew = defer ? m_r : fmaxf(m_r, vmax);
      float psum = 0.f;
#pragma unroll
      for (int s = 0; s < 4; ++s)
#pragma unroll
        for (int r = 0; r < 4; ++r) {
          vv[s][r] = __expf(vv[s][r] - mnew);
          psum += vv[s][r];
        }
      psum += __shfl_xor(psum, 16);
      psum += __shfl_xor(psum, 32);

      // pack P to bf16 pairs, write swizzled
#pragma unroll
      for (int s = 0; s < 4; ++s)
#pragma unroll
        for (int t = 0; t < 2; ++t) {
          unsigned int w;
          asm("v_cvt_pk_bf16_f32 %0, %1, %2" : "=v"(w) : "v"(vv[s][2 * t]), "v"(vv[s][2 * t + 1]));
          int u16off = lr * 64 + ((s * 2 + (lg >> 1)) ^ swz) * 8 + (lg & 1) * 4 + t * 2;
          *(unsigned int*)&Pw[wid][u16off] = w;
        }

      // rescale (skipped when deferred) — VALU here overlaps the Pw ds_write latency
      if (!defer) {
        float corr = __expf(m_r - mnew);
        l_r *= corr;
        m_r = mnew;
        float crr[4];
#pragma unroll
        for (int r = 0; r < 4; ++r) crr[r] = __shfl(corr, lg * 4 + r);
#pragma unroll
        for (int n = 0; n < 8; ++n)
#pragma unroll
          for (int r = 0; r < 4; ++r) o[n][r] *= crr[r];
      }
      l_r += psum;

      asm volatile("s_waitcnt lgkmcnt(0)" ::: "memory");
      SCHEDB();
      // PV: A = P[q=lr][k-chunk], B = Vt[dv=n*16+lr][k-chunk]
      bf16x8 pa0 = *(const bf16x8*)&Pw[wid][lr * 64 + (lg ^ swz) * 8];
      bf16x8 pa1 = *(const bf16x8*)&Pw[wid][lr * 64 + ((4 + lg) ^ swz) * 8];
      __builtin_amdgcn_s_setprio(1);
#pragma unroll
      for (int n = 0; n < 8; ++n) {
        bf16x8 vb0 = *(const bf16x8*)&Vt[(n * 16 + lr) * 64 + (lg ^ swz) * 8];
        bf16x8 vb1 = *(const bf16x8*)&Vt[(n * 16 + lr) * 64 + ((4 + lg) ^ swz) * 8];
        o[n] = mfma16(pa0, vb0, o[n]);
        o[n] = mfma16(pa1, vb1, o[n]);
      }
      __builtin_amdgcn_s_setprio(0);
    }

    float linv = 1.f / l_r;
    float lnv[4];
#pragma unroll
    for (int r = 0; r < 4; ++r) lnv[r] = __shfl(linv, lg * 4 + r);
#pragma unroll
    for (int n = 0; n < 8; ++n)
#pragma unroll
      for (int r = 0; r < 4; ++r) {
        float val = o[n][r] * lnv[r];
        AttO[(rowb + q0 + wid * 16 + lg * 4 + r) * (size_t)(HH * 128) + h * 128 + n * 16 + lr] =
            f2bf(val);
      }
  }
}

// ---------- launch ----------
extern "C" void kernel_launch(void* const* d_in, const int* in_sizes, int n_in,
                              void* d_out, int out_size, void* d_ws, size_t ws_size,
                              hipStream_t stream) {
  const float* x       = (const float*)d_in[0];
  const float* wq_sem  = (const float*)d_in[1];
  const float* wk_sem  = (const float*)d_in[2];
  const float* wq_geo  = (const float*)d_in[3];
  const float* wk_geo  = (const float*)d_in[4];
  const float* wv      = (const float*)d_in[5];
  const float* wo      = (const float*)d_in[6];
  const float* gate    = (const float*)d_in[7];

  char* ws = (char*)d_ws;
  // layout (bytes):
  //  Xbf   @ 0           : 16,777,216   (reused later as AttO)
  //  WcatT @ 16,777,216  : 25,165,824
  //  WoT   @ 41,943,040  :  8,388,608
  //  P     @ 50,331,648  : 33,554,432   (4096 x 4096 bf16: qsem|ksem|qgeo|kgeo)
  //  VtG   @ 83,886,080  : 16,777,216
  //  cosT  @ 100,663,296 : 262,144 ; sinT follows
  u16* Xbf   = (u16*)(ws);
  u16* WcatT = (u16*)(ws + 16777216);
  u16* WoT   = (u16*)(ws + 41943040);
  u16* P     = (u16*)(ws + 50331648);
  u16* VtG   = (u16*)(ws + 83886080);
  float* cosT = (float*)(ws + 100663296);
  float* sinT = cosT + 2048 * 32;
  u16* AttO = Xbf;    // Xbf dead after projection GEMM

  dim3 tb(32, 8);
  prep_all_k<<<dim3(64, 64, 8), tb, 0, stream>>>(x, wq_sem, wk_sem, wq_geo, wk_geo,
                                                 wv, wo, WcatT, WoT, Xbf, cosT, sinT);

  // proj: BN=384 -> grid 16x32 = 512 blocks; Q/K cols -> P, V cols -> VtG (transposed)
  gemm4_k<6, false, true><<<dim3(16, 32), 256, 0, stream>>>(Xbf, WcatT, P, VtG,
                                                            4096, 6144, 2048);
  // vectorized in-place RoPE on P kgeo only (Q-rope folded into attn)
  rope_k<<<1024, 256, 0, stream>>>(P, cosT, sinT);
  attn_k<<<dim3(256, 2), 256, 0, stream>>>(P, VtG, gate, cosT, sinT, AttO);
  // wo: BN=256 -> grid 8x32 = 256 blocks = 1 balanced round
  gemm4_k<4, true, false><<<dim3(8, 32), 256, 0, stream>>>(AttO, WoT, d_out, nullptr,
                                                           4096, 2048, 2048);
}